// Round 5
// baseline (14566.685 us; speedup 1.0000x reference)
//
#include <hip/hip_runtime.h>

typedef __attribute__((ext_vector_type(8))) __bf16 bf16x8;
typedef __attribute__((ext_vector_type(4))) float f32x4;
typedef __attribute__((ext_vector_type(8))) unsigned short u16x8;

#define B_ROWS 131072
#define EDIM   256
#define N_E    1024
#define BMR    64          // rows per block
#define ZSTR   260         // LDS z row stride (floats); 65 granules => bank spread
#define CHUNKS 16          // per wave: 16 chunks x 16 codes = 256 codes
#define CAP    16

#define OUT1 ((size_t)B_ROWS * EDIM)       // loss scalar
#define OUT2 (OUT1 + 1)                    // indices [B]
#define OUT3 (OUT2 + B_ROWS)               // perplexity scalar

// ws layout
#define WS_EMB16 0          // 1024*256 ushort = 524288 B
#define WS_ESQ   524288     // 1024 float
#define WS_COUNT 528384     // 1024 uint
#define WS_LOSS  532480     // 1 double

__device__ __forceinline__ unsigned short f2bf(float f) {   // RN to bf16
    unsigned u = __float_as_uint(f);
    return (unsigned short)((u + 0x7FFFu + ((u >> 16) & 1u)) >> 16);
}
__device__ __forceinline__ unsigned encf(float f) {          // order-preserving
    unsigned u = __float_as_uint(f);
    return u ^ (unsigned)(((int)u >> 31) | 0x80000000);
}
__device__ __forceinline__ float decf(unsigned x) {
    return (x & 0x80000000u) ? __uint_as_float(x ^ 0x80000000u)
                             : __uint_as_float(~x);
}

// numpy pairwise sum-of-squares over 128 elems (exact tree, no contraction).
// float4 loads; element->accumulator mapping identical to the scalar version.
__device__ inline float pw128_sq(const float* p) {
    float4 v0 = *(const float4*)p, v1 = *(const float4*)(p + 4);
    float r[8];
    r[0] = __fmul_rn(v0.x, v0.x); r[1] = __fmul_rn(v0.y, v0.y);
    r[2] = __fmul_rn(v0.z, v0.z); r[3] = __fmul_rn(v0.w, v0.w);
    r[4] = __fmul_rn(v1.x, v1.x); r[5] = __fmul_rn(v1.y, v1.y);
    r[6] = __fmul_rn(v1.z, v1.z); r[7] = __fmul_rn(v1.w, v1.w);
    for (int i = 8; i < 128; i += 8) {
        v0 = *(const float4*)(p + i); v1 = *(const float4*)(p + i + 4);
        r[0] = __fadd_rn(r[0], __fmul_rn(v0.x, v0.x));
        r[1] = __fadd_rn(r[1], __fmul_rn(v0.y, v0.y));
        r[2] = __fadd_rn(r[2], __fmul_rn(v0.z, v0.z));
        r[3] = __fadd_rn(r[3], __fmul_rn(v0.w, v0.w));
        r[4] = __fadd_rn(r[4], __fmul_rn(v1.x, v1.x));
        r[5] = __fadd_rn(r[5], __fmul_rn(v1.y, v1.y));
        r[6] = __fadd_rn(r[6], __fmul_rn(v1.z, v1.z));
        r[7] = __fadd_rn(r[7], __fmul_rn(v1.w, v1.w));
    }
    float s01 = __fadd_rn(r[0], r[1]), s23 = __fadd_rn(r[2], r[3]);
    float s45 = __fadd_rn(r[4], r[5]), s67 = __fadd_rn(r[6], r[7]);
    return __fadd_rn(__fadd_rn(s01, s23), __fadd_rn(s45, s67));
}

// exact fp32 distance, bit-identical to the verified rounds-1..4 chain
__device__ inline float exact_d(const float* zp, const float* ep, float zsq, float eq) {
    const float4* z4 = (const float4*)zp;
    const float4* e4 = (const float4*)ep;
    float acc = 0.f;
#pragma unroll 8
    for (int k = 0; k < 64; ++k) {
        float4 a = z4[k], b = e4[k];
        acc = __fmaf_rn(a.x, b.x, acc);
        acc = __fmaf_rn(a.y, b.y, acc);
        acc = __fmaf_rn(a.z, b.z, acc);
        acc = __fmaf_rn(a.w, b.w, acc);
    }
    return __fsub_rn(__fadd_rn(zsq, eq), 2.0f * acc);
}

__global__ void prep_emb(const float* __restrict__ emb,
                         unsigned short* __restrict__ emb16,
                         float* __restrict__ esqg)
{
    int n = blockIdx.x, t = threadIdx.x;          // 1024 blocks x 64 threads
    const float4 v = ((const float4*)(emb + (size_t)n * EDIM))[t];
    ushort4 o = { f2bf(v.x), f2bf(v.y), f2bf(v.z), f2bf(v.w) };
    ((ushort4*)(emb16 + (size_t)n * EDIM))[t] = o;
    if (t < 2) {
        float h = pw128_sq(emb + (size_t)n * EDIM + 128 * t);
        float ho = __shfl_xor(h, 1);
        if (t == 0) esqg[n] = __fadd_rn(h, ho);
    }
}

__global__ __launch_bounds__(256, 2) void vq_main(
    const float* __restrict__ z, const float* __restrict__ emb,
    const unsigned short* __restrict__ emb16, const float* __restrict__ esqg,
    float* __restrict__ out, unsigned int* __restrict__ count,
    double* __restrict__ lossSum)
{
    __shared__ float zls[BMR * ZSTR];                // 66,560 B (fp32 z tile)
    __shared__ float esq_s[N_E];
    __shared__ float zsq_s[BMR], S_s[BMR], thr_s[BMR];
    __shared__ float Mb[1];
    __shared__ unsigned long long wd64[4][BMR];
    __shared__ unsigned cnt[BMR];
    __shared__ int list[BMR][CAP];
    __shared__ int rowbest[BMR];
    __shared__ double red[256];

    const int tid  = threadIdx.x;
    const int blk  = blockIdx.x;
    const int lane = tid & 63;
    const int wave = tid >> 6;
    const int col  = lane & 15;
    const int quad = lane >> 4;

    // ---- stage z fp32 -> LDS (coalesced float4) ----
    const float4* zg = (const float4*)(z + (size_t)blk * BMR * EDIM);
#pragma unroll
    for (int it = 0; it < 16; ++it) {
        int fidx = it * 256 + tid;
        int m = fidx >> 6, k4 = fidx & 63;
        *(float4*)&zls[m * ZSTR + k4 * 4] = zg[fidx];
    }
    for (int i = tid; i < N_E; i += 256) esq_s[i] = esqg[i];
    if (tid < BMR) cnt[tid] = 0u;
    __syncthreads();

    // ---- A fragments from LDS fp32 (one-time), all 64 rows resident ----
    bf16x8 afr[4][8];
#pragma unroll
    for (int m = 0; m < 4; ++m) {
        int row = m * 16 + col;
#pragma unroll
        for (int ks = 0; ks < 8; ++ks) {
            const float* p = &zls[row * ZSTR + (ks * 4 + quad) * 8];
            float4 a0 = *(const float4*)p;
            float4 a1 = *(const float4*)(p + 4);
            u16x8 t = { f2bf(a0.x), f2bf(a0.y), f2bf(a0.z), f2bf(a0.w),
                        f2bf(a1.x), f2bf(a1.y), f2bf(a1.z), f2bf(a1.w) };
            afr[m][ks] = *(bf16x8*)&t;
        }
    }

    // ---- exact zsq (np-pairwise, from LDS) + S = sum|z| (bound only) ----
    if (tid < 128) {
        int row = tid >> 1, half = tid & 1;
        const float* p = &zls[row * ZSTR + half * 128];
        float h = pw128_sq(p);
        const float4* p4 = (const float4*)p;
        float4 sv = {0.f, 0.f, 0.f, 0.f};
#pragma unroll
        for (int jj = 0; jj < 32; ++jj) {
            float4 vv = p4[jj];
            sv.x += fabsf(vv.x); sv.y += fabsf(vv.y);
            sv.z += fabsf(vv.z); sv.w += fabsf(vv.w);
        }
        float sa = (sv.x + sv.y) + (sv.z + sv.w);
        float ho = __shfl_xor(h, 1);
        float so = __shfl_xor(sa, 1);
        if (half == 0) {
            zsq_s[row] = __fadd_rn(h, ho);
            S_s[row]   = (sa + so) * 1.001f;
        }
    }
    __syncthreads();
    if (tid < 64) {                       // block margin M = S_max/131072 + 1e-4
        float v = S_s[tid];
#pragma unroll
        for (int m2 = 1; m2 <= 32; m2 <<= 1) v = fmaxf(v, __shfl_xor(v, m2));
        if (tid == 0) Mb[0] = v * (1.0f / 131072.0f) + 1e-4f;
    }
    __syncthreads();
    const float Mblk = Mb[0];

    // ================= barrier-free chunk loop ==============================
    float bd[16]; int bc[16];
#pragma unroll
    for (int i2 = 0; i2 < 16; ++i2) { bd[i2] = INFINITY; bc[i2] = 0; }
    float    bufS[3] = {INFINITY, INFINITY, INFINITY};
    unsigned bufP[3] = {0, 0, 0};
    unsigned ovf = 0;

    const int mycode0 = wave * 256 + col;
    const unsigned short* ebase = emb16 + ((size_t)mycode0 << 8) + (quad << 3);

    for (int c = 0; c < CHUNKS; ++c) {
        const u16x8* bp = (const u16x8*)(ebase + ((size_t)c << 12));
        u16x8 bfr[8];
#pragma unroll
        for (int ks = 0; ks < 8; ++ks) bfr[ks] = bp[ks * 4];   // code-row k-slices
        const int codeL = mycode0 + c * 16;
        const float eqv = esq_s[codeL];
        f32x4 acc[4];
#pragma unroll
        for (int m = 0; m < 4; ++m) acc[m] = (f32x4){0.f, 0.f, 0.f, 0.f};
#pragma unroll
        for (int ks = 0; ks < 8; ++ks) {
            bf16x8 b = *(bf16x8*)&bfr[ks];
#pragma unroll
            for (int m = 0; m < 4; ++m)
                acc[m] = __builtin_amdgcn_mfma_f32_16x16x32_bf16(afr[m][ks], b, acc[m], 0, 0, 0);
        }
#pragma unroll
        for (int m = 0; m < 4; ++m)
#pragma unroll
            for (int r = 0; r < 4; ++r) {
                const int slot = m * 4 + r;
                float s = __fmaf_rn(-2.0f, acc[m][r], eqv);
                float old = bd[slot];
                bool isnew = s < old;
                float ls = isnew ? old : s;
                int   lc = isnew ? bc[slot] : codeL;
                if (isnew) { bd[slot] = s; bc[slot] = codeL; }
                if (fabsf(s - old) <= Mblk) {       // loser is a potential candidate
                    const unsigned lp = ((unsigned)(m * 16 + quad * 4 + r) << 10) | (unsigned)lc;
                    bool done = false;
#pragma unroll
                    for (int b2 = 0; b2 < 3; ++b2) {
                        bool take = (!done) && (bufS[b2] == INFINITY);
                        if (take) { bufS[b2] = ls; bufP[b2] = lp; done = true; }
                    }
                    if (!done) {
                        // prune entries that can no longer qualify (sound: rowmin <= bd)
#pragma unroll
                        for (int b2 = 0; b2 < 3; ++b2) {
                            unsigned er = bufP[b2] >> 10;
                            float bdv = INFINITY;
#pragma unroll
                            for (int m2 = 0; m2 < 4; ++m2)
#pragma unroll
                                for (int r2 = 0; r2 < 4; ++r2)
                                    if (er == (unsigned)(m2 * 16 + quad * 4 + r2)) bdv = bd[m2 * 4 + r2];
                            if (bufS[b2] > bdv + Mblk) bufS[b2] = INFINITY;
                        }
#pragma unroll
                        for (int b2 = 0; b2 < 3; ++b2) {
                            bool take = (!done) && (bufS[b2] == INFINITY);
                            if (take) { bufS[b2] = ls; bufP[b2] = lp; done = true; }
                        }
                        if (!done) ovf |= (1u << slot);
                    }
                }
            }
    }

    // ---- cross-lane reduce per slot (lex min on (score, code)) ----
#pragma unroll
    for (int m = 0; m < 4; ++m)
#pragma unroll
        for (int r = 0; r < 4; ++r) {
            const int slot = m * 4 + r;
            unsigned long long kk = ((unsigned long long)encf(bd[slot]) << 32) | (unsigned)bc[slot];
#pragma unroll
            for (int msk = 1; msk <= 8; msk <<= 1) {
                unsigned long long o = __shfl_xor(kk, msk);
                if (o < kk) kk = o;
            }
            if (col == 0) wd64[wave][m * 16 + quad * 4 + r] = kk;
        }
    __syncthreads();
    if (tid < BMR) {
        unsigned long long b0 = wd64[0][tid], b1 = wd64[1][tid];
        unsigned long long b2 = wd64[2][tid], b3 = wd64[3][tid];
        unsigned long long mn = b0 < b1 ? b0 : b1;
        unsigned long long mn2 = b2 < b3 ? b2 : b3;
        if (mn2 < mn) mn = mn2;
        thr_s[tid] = decf((unsigned)(mn >> 32)) + (S_s[tid] * (1.0f / 131072.0f) + 1e-4f);
    }
    __syncthreads();

    // ---- candidate push ----
#pragma unroll
    for (int m = 0; m < 4; ++m)
#pragma unroll
        for (int r = 0; r < 4; ++r) {
            const int slot = m * 4 + r;
            const int row = m * 16 + quad * 4 + r;
            if (bd[slot] <= thr_s[row]) {
                unsigned i = atomicAdd(&cnt[row], 1u);
                if (i < CAP) list[row][i] = bc[slot];
            }
            if (ovf & (1u << slot)) atomicAdd(&cnt[row], 1000u);
        }
#pragma unroll
    for (int b2 = 0; b2 < 3; ++b2)
        if (bufS[b2] != INFINITY) {
            int row = (int)(bufP[b2] >> 10);
            if (bufS[b2] <= thr_s[row]) {
                unsigned i = atomicAdd(&cnt[row], 1u);
                if (i < CAP) list[row][i] = (int)(bufP[b2] & 1023u);
            }
        }
    __syncthreads();

    // ---- exact rescore of candidates (4 lanes / row, z from LDS) ----
    {
        int row = tid >> 2, j = tid & 3;
        int cn = (int)cnt[row];
        unsigned long long bkey = ~0ull;
        float zq = zsq_s[row];
        if (cn <= CAP) {
            for (int i = j; i < cn; i += 4) {
                int n = list[row][i];
                float d = exact_d(&zls[row * ZSTR], emb + (size_t)n * EDIM, zq, esq_s[n]);
                unsigned long long k2 = ((unsigned long long)encf(d) << 32) | (unsigned)n;
                if (k2 < bkey) bkey = k2;
            }
        }
#pragma unroll
        for (int m = 1; m <= 2; m <<= 1) {
            unsigned long long o = __shfl_xor(bkey, m);
            if (o < bkey) bkey = o;
        }
        if (j == 0) rowbest[row] = (cn <= CAP) ? (int)(bkey & 0xFFFFFFFFu) : -1;
    }
    __syncthreads();

    // ---- overflow rows: full exact scan, block-cooperative (rare) ----
    {
        unsigned long long* red64 = (unsigned long long*)red;
        for (int r = 0; r < BMR; ++r) {
            if (rowbest[r] != -1) continue;       // uniform branch
            float zqr = zsq_s[r];
            unsigned long long k = ~0ull;
            for (int ci = 0; ci < 4; ++ci) {
                int n = tid + ci * 256;
                float d = exact_d(&zls[r * ZSTR], emb + (size_t)n * EDIM, zqr, esq_s[n]);
                unsigned long long k2 = ((unsigned long long)encf(d) << 32) | (unsigned)n;
                if (k2 < k) k = k2;
            }
            red64[tid] = k; __syncthreads();
            for (int sR = 128; sR > 0; sR >>= 1) {
                if (tid < sR && red64[tid + sR] < red64[tid]) red64[tid] = red64[tid + sR];
                __syncthreads();
            }
            if (tid == 0) rowbest[r] = (int)(red64[0] & 0xFFFFFFFFu);
            __syncthreads();
        }
    }
    __syncthreads();

    // ---- epilogue: gather z_q, STE, loss partial, index, histogram ----
    {
        const int row = tid >> 2, q = tid & 3;
        const size_t grow = (size_t)blk * BMR + row;
        const int bn = rowbest[row];
        const float4* ebr = (const float4*)(emb + (size_t)bn * EDIM);
        float4* outr = (float4*)(out + grow * EDIM);
        double lacc = 0.0;
#pragma unroll
        for (int i = 0; i < 16; ++i) {
            int k4 = q + i * 4;
            float4 zv = *(const float4*)&zls[row * ZSTR + k4 * 4];
            float4 ev = ebr[k4];
            float4 o; float sd;
            sd = __fsub_rn(ev.x, zv.x); o.x = __fadd_rn(zv.x, sd); lacc += (double)__fmul_rn(sd, sd);
            sd = __fsub_rn(ev.y, zv.y); o.y = __fadd_rn(zv.y, sd); lacc += (double)__fmul_rn(sd, sd);
            sd = __fsub_rn(ev.z, zv.z); o.z = __fadd_rn(zv.z, sd); lacc += (double)__fmul_rn(sd, sd);
            sd = __fsub_rn(ev.w, zv.w); o.w = __fadd_rn(zv.w, sd); lacc += (double)__fmul_rn(sd, sd);
            outr[k4] = o;
        }
        if (q == 0) {
            out[OUT2 + grow] = (float)bn;
            atomicAdd(&count[bn], 1u);
        }
        red[tid] = lacc;
        __syncthreads();
        for (int sR = 128; sR > 0; sR >>= 1) {
            if (tid < sR) red[tid] += red[tid + sR];
            __syncthreads();
        }
        if (tid == 0) atomicAdd(lossSum, red[0]);
    }
}

__global__ void vq_finalize(const unsigned int* __restrict__ count,
                            const double* __restrict__ lossSum,
                            float* __restrict__ out)
{
    __shared__ double red[1024];
    int t = threadIdx.x;
    double em = (double)count[t] * (1.0 / 131072.0);
    red[t] = em * log(em + 1e-10);
    __syncthreads();
    for (int s = 512; s > 0; s >>= 1) {
        if (t < s) red[t] += red[t + s];
        __syncthreads();
    }
    if (t == 0) {
        out[OUT3] = (float)exp(-red[0]);
        double m = lossSum[0] * (1.0 / 33554432.0);
        out[OUT1] = (float)(1.25 * m);
    }
}

extern "C" void kernel_launch(void* const* d_in, const int* in_sizes, int n_in,
                              void* d_out, int out_size, void* d_ws, size_t ws_size,
                              hipStream_t stream) {
    const float* z   = (const float*)d_in[0];
    const float* emb = (const float*)d_in[1];
    float* out = (float*)d_out;

    unsigned short* emb16 = (unsigned short*)((char*)d_ws + WS_EMB16);
    float* esqg           = (float*)((char*)d_ws + WS_ESQ);
    unsigned int* count   = (unsigned int*)((char*)d_ws + WS_COUNT);
    double* lossSum       = (double*)((char*)d_ws + WS_LOSS);

    hipMemsetAsync((char*)d_ws + WS_COUNT, 0, 4104, stream);
    prep_emb<<<N_E, 64, 0, stream>>>(emb, emb16, esqg);
    vq_main<<<B_ROWS / BMR, 256, 0, stream>>>(z, emb, emb16, esqg, out, count, lossSum);
    vq_finalize<<<1, 1024, 0, stream>>>(count, lossSum, out);
}

// Round 6
// 14336.060 us; speedup vs baseline: 1.0161x; 1.0161x over previous
//
#include <hip/hip_runtime.h>

typedef __attribute__((ext_vector_type(8))) __bf16 bf16x8;
typedef __attribute__((ext_vector_type(4))) float f32x4;
typedef __attribute__((ext_vector_type(8))) unsigned short u16x8;

#define B_ROWS 131072
#define EDIM   256
#define N_E    1024
#define BMR    64          // rows per block
#define CHUNKS 32          // 32 chunks x 32 codes
#define CAP    8

#define OUT1 ((size_t)B_ROWS * EDIM)       // loss scalar
#define OUT2 (OUT1 + 1)                    // indices [B]
#define OUT3 (OUT2 + B_ROWS)               // perplexity scalar

// ws layout
#define WS_EMB16 0          // 1024*256 ushort = 524288 B (PRE-SWIZZLED rows)
#define WS_ESQ   524288     // 1024 float
#define WS_COUNT 528384     // 1024 uint
#define WS_LOSS  532480     // 1 double

__device__ __forceinline__ unsigned short f2bf(float f) {   // RN to bf16
    unsigned u = __float_as_uint(f);
    return (unsigned short)((u + 0x7FFFu + ((u >> 16) & 1u)) >> 16);
}
__device__ __forceinline__ unsigned encf(float f) {          // order-preserving
    unsigned u = __float_as_uint(f);
    return u ^ (unsigned)(((int)u >> 31) | 0x80000000);
}

// async global->LDS, 16B per lane (linear dest = wave-uniform base + lane*16)
__device__ __forceinline__ void gload16(const void* g, void* l) {
    __builtin_amdgcn_global_load_lds(
        (const __attribute__((address_space(1))) unsigned int*)g,
        (__attribute__((address_space(3))) unsigned int*)l, 16, 0, 0);
}

// numpy pairwise sum-of-squares over 128 elems (exact tree, no contraction)
__device__ inline float pw128_sq(const float* p) {
    float4 v0 = *(const float4*)p, v1 = *(const float4*)(p + 4);
    float r[8];
    r[0] = __fmul_rn(v0.x, v0.x); r[1] = __fmul_rn(v0.y, v0.y);
    r[2] = __fmul_rn(v0.z, v0.z); r[3] = __fmul_rn(v0.w, v0.w);
    r[4] = __fmul_rn(v1.x, v1.x); r[5] = __fmul_rn(v1.y, v1.y);
    r[6] = __fmul_rn(v1.z, v1.z); r[7] = __fmul_rn(v1.w, v1.w);
    for (int i = 8; i < 128; i += 8) {
        v0 = *(const float4*)(p + i); v1 = *(const float4*)(p + i + 4);
        r[0] = __fadd_rn(r[0], __fmul_rn(v0.x, v0.x));
        r[1] = __fadd_rn(r[1], __fmul_rn(v0.y, v0.y));
        r[2] = __fadd_rn(r[2], __fmul_rn(v0.z, v0.z));
        r[3] = __fadd_rn(r[3], __fmul_rn(v0.w, v0.w));
        r[4] = __fadd_rn(r[4], __fmul_rn(v1.x, v1.x));
        r[5] = __fadd_rn(r[5], __fmul_rn(v1.y, v1.y));
        r[6] = __fadd_rn(r[6], __fmul_rn(v1.z, v1.z));
        r[7] = __fadd_rn(r[7], __fmul_rn(v1.w, v1.w));
    }
    float s01 = __fadd_rn(r[0], r[1]), s23 = __fadd_rn(r[2], r[3]);
    float s45 = __fadd_rn(r[4], r[5]), s67 = __fadd_rn(r[6], r[7]);
    return __fadd_rn(__fadd_rn(s01, s23), __fadd_rn(s45, s67));
}

// exact fp32 distance, bit-identical to the verified rounds-1..5 chain
__device__ inline float exact_d(const float* zp, const float* ep, float zsq, float eq) {
    const float4* z4 = (const float4*)zp;
    const float4* e4 = (const float4*)ep;
    float acc = 0.f;
#pragma unroll 8
    for (int k = 0; k < 64; ++k) {
        float4 a = z4[k], b = e4[k];
        acc = __fmaf_rn(a.x, b.x, acc);
        acc = __fmaf_rn(a.y, b.y, acc);
        acc = __fmaf_rn(a.z, b.z, acc);
        acc = __fmaf_rn(a.w, b.w, acc);
    }
    return __fsub_rn(__fadd_rn(zsq, eq), 2.0f * acc);
}

// emb fp32 -> bf16 with rows stored PRE-SWIZZLED: granule g lands at g^(n&7)
__global__ void prep_emb(const float* __restrict__ emb,
                         unsigned short* __restrict__ emb16,
                         float* __restrict__ esqg)
{
    int n = blockIdx.x, t = threadIdx.x;          // 1024 blocks x 64 threads
    const float4 v = ((const float4*)(emb + (size_t)n * EDIM))[t];
    ushort4 o = { f2bf(v.x), f2bf(v.y), f2bf(v.z), f2bf(v.w) };
    int g = t >> 1, j0 = (t & 1) * 4;
    int didx = (((g ^ (n & 7)) << 3) + j0);
    *(ushort4*)(emb16 + (size_t)n * EDIM + didx) = o;
    if (t < 2) {
        float h = pw128_sq(emb + (size_t)n * EDIM + 128 * t);
        float ho = __shfl_xor(h, 1);
        if (t == 0) esqg[n] = __fadd_rn(h, ho);
    }
}

__global__ __launch_bounds__(256, 4) void vq_main(
    const float* __restrict__ z, const float* __restrict__ emb,
    const unsigned short* __restrict__ emb16, const float* __restrict__ esqg,
    float* __restrict__ out, unsigned int* __restrict__ count,
    double* __restrict__ lossSum)
{
    __shared__ unsigned short et[2][32 * EDIM];      // 2 x 16 KB (swizzled rows)
    __shared__ float esq_s[N_E];                     // 4 KB
    __shared__ float zsq_s[BMR], S_s[BMR];
    __shared__ float Mb[1];
    __shared__ unsigned cnt[BMR];
    __shared__ unsigned short list[BMR][CAP];        // 1 KB
    __shared__ int rowbest[BMR];
    __shared__ double red4[4];
    __shared__ unsigned long long fb4[4];

    const int tid  = threadIdx.x;
    const int blk  = blockIdx.x;
    const int lane = tid & 63;
    const int w    = tid >> 6;
    const int col  = lane & 15;
    const int quad = lane >> 4;
    const int nt   = w >> 1;       // code half (0/1)
    const int mh   = w & 1;        // row half (rows 32*mh..+32)

    const float* zb = z + (size_t)blk * BMR * EDIM;

    // ---- stage e chunk 0 (async, linear dest; source is pre-swizzled) ----
#pragma unroll
    for (int r2 = 0; r2 < 4; ++r2) {
        int G2 = r2 * 256 + tid;
        gload16(emb16 + (size_t)G2 * 8, &et[0][G2 * 8]);
    }
    for (int i = tid; i < N_E; i += 256) esq_s[i] = esqg[i];
    if (tid < BMR) cnt[tid] = 0u;

    // ---- A fragments from global z (one-time) ----
    bf16x8 afr[2][8];
#pragma unroll
    for (int mti = 0; mti < 2; ++mti) {
        int row = 32 * mh + 16 * mti + col;
#pragma unroll
        for (int ks = 0; ks < 8; ++ks) {
            const float* p = zb + row * EDIM + ((ks * 4 + quad) << 3);
            float4 a0 = *(const float4*)p;
            float4 a1 = *(const float4*)(p + 4);
            u16x8 t = { f2bf(a0.x), f2bf(a0.y), f2bf(a0.z), f2bf(a0.w),
                        f2bf(a1.x), f2bf(a1.y), f2bf(a1.z), f2bf(a1.w) };
            afr[mti][ks] = *(bf16x8*)&t;
        }
    }

    // ---- exact zsq (np-pairwise) + S = sum|z| (bound only) ----
    if (tid < 128) {
        int row = tid >> 1, half = tid & 1;
        const float* p = zb + row * EDIM + half * 128;
        float h = pw128_sq(p);
        const float4* p4 = (const float4*)p;
        float4 sv = {0.f, 0.f, 0.f, 0.f};
#pragma unroll
        for (int jj = 0; jj < 32; ++jj) {
            float4 vv = p4[jj];
            sv.x += fabsf(vv.x); sv.y += fabsf(vv.y);
            sv.z += fabsf(vv.z); sv.w += fabsf(vv.w);
        }
        float sa = (sv.x + sv.y) + (sv.z + sv.w);
        float ho = __shfl_xor(h, 1);
        float so = __shfl_xor(sa, 1);
        if (half == 0) {
            zsq_s[row] = __fadd_rn(h, ho);
            S_s[row]   = (sa + so) * 1.001f;
        }
    }
    __syncthreads();
    if (tid < 64) {                       // block margin M = S_max/65536 + 1e-4
        float v = S_s[tid];
#pragma unroll
        for (int m2 = 1; m2 <= 32; m2 <<= 1) v = fmaxf(v, __shfl_xor(v, m2));
        if (tid == 0) Mb[0] = v * (1.0f / 65536.0f) + 1e-4f;
    }
    __syncthreads();
    const float Mblk = Mb[0];

    const int erow  = nt * 16 + col;
    const int rowb0 = 32 * mh + 4 * quad;            // + 16*mti + r

    // ================= single-pass chunk loop =============================
    float bd[2][4]; int bc[2][4];
#pragma unroll
    for (int mti = 0; mti < 2; ++mti)
#pragma unroll
        for (int r = 0; r < 4; ++r) { bd[mti][r] = INFINITY; bc[mti][r] = 0; }

    for (int c = 0; c < CHUNKS; ++c) {
        if (c + 1 < CHUNKS) {            // async prefetch of next chunk -> LDS
#pragma unroll
            for (int r2 = 0; r2 < 4; ++r2) {
                int G2 = r2 * 256 + tid;
                gload16(emb16 + (size_t)(c + 1) * 32 * EDIM + (size_t)G2 * 8,
                        &et[(c + 1) & 1][G2 * 8]);
            }
        }
        const unsigned short* eb = &et[c & 1][0];
        f32x4 acc0 = {0.f, 0.f, 0.f, 0.f}, acc1 = {0.f, 0.f, 0.f, 0.f};
#pragma unroll
        for (int ks = 0; ks < 8; ++ks) {
            bf16x8 b = *(const bf16x8*)&eb[erow * EDIM + (((ks * 4 + quad) ^ (erow & 7)) << 3)];
            acc0 = __builtin_amdgcn_mfma_f32_16x16x32_bf16(afr[0][ks], b, acc0, 0, 0, 0);
            acc1 = __builtin_amdgcn_mfma_f32_16x16x32_bf16(afr[1][ks], b, acc1, 0, 0, 0);
        }
        const int codeN = c * 32 + erow;
        const float eqv = esq_s[codeN];
#pragma unroll
        for (int mti = 0; mti < 2; ++mti)
#pragma unroll
            for (int r = 0; r < 4; ++r) {
                float s   = __fmaf_rn(-2.0f, (mti ? acc1[r] : acc0[r]), eqv);
                float old = bd[mti][r];
                bool isnew = s < old;
                float ls = fmaxf(s, old);
                int   lc = isnew ? bc[mti][r] : codeN;
                bd[mti][r] = fminf(s, old);
                bc[mti][r] = isnew ? codeN : bc[mti][r];
                // sound gate: loser qualifies iff |s-old| <= M  (ls - bd_new <= M)
                if (__builtin_expect(fabsf(s - old) <= Mblk, 0)) {
                    int row = rowb0 + 16 * mti + r;
                    unsigned i = atomicAdd(&cnt[row], 1u);
                    if (i < CAP) list[row][i] = (unsigned short)lc;
                }
            }
        __syncthreads();
    }

    // ---- cross-col reduce per slot, push finals (2 per row: nt=0,1) ----
#pragma unroll
    for (int mti = 0; mti < 2; ++mti)
#pragma unroll
        for (int r = 0; r < 4; ++r) {
            unsigned long long kk =
                ((unsigned long long)encf(bd[mti][r]) << 32) | (unsigned)bc[mti][r];
#pragma unroll
            for (int msk = 1; msk <= 8; msk <<= 1) {
                unsigned long long o = __shfl_xor(kk, msk);
                if (o < kk) kk = o;
            }
            if (col == 0) {
                int row = rowb0 + 16 * mti + r;
                unsigned i = atomicAdd(&cnt[row], 1u);
                if (i < CAP) list[row][i] = (unsigned short)(kk & 0xFFFFu);
            }
        }
    __syncthreads();

    // ---- exact rescore of candidates (4 lanes / row, z from L2) ----
    {
        int row = tid >> 2, j = tid & 3;
        int cn = (int)cnt[row];
        unsigned long long bkey = ~0ull;
        float zq = zsq_s[row];
        const float* zrow = zb + row * EDIM;
        if (cn <= CAP) {
            for (int i = j; i < cn; i += 4) {
                int n = (int)list[row][i];
                float d = exact_d(zrow, emb + (size_t)n * EDIM, zq, esq_s[n]);
                unsigned long long k2 = ((unsigned long long)encf(d) << 32) | (unsigned)n;
                if (k2 < bkey) bkey = k2;
            }
        }
#pragma unroll
        for (int m = 1; m <= 2; m <<= 1) {
            unsigned long long o = __shfl_xor(bkey, m);
            if (o < bkey) bkey = o;
        }
        if (j == 0) rowbest[row] = (cn <= CAP) ? (int)(bkey & 0xFFFFFFFFu) : -1;
    }
    __syncthreads();

    // ---- overflow rows: full exact scan, block-cooperative (rare) ----
    for (int r = 0; r < BMR; ++r) {
        if (rowbest[r] != -1) continue;       // uniform branch
        const float* zr = zb + r * EDIM;
        float zqr = zsq_s[r];
        unsigned long long k = ~0ull;
        for (int ci = 0; ci < 4; ++ci) {
            int n = tid + ci * 256;
            float d = exact_d(zr, emb + (size_t)n * EDIM, zqr, esq_s[n]);
            unsigned long long k2 = ((unsigned long long)encf(d) << 32) | (unsigned)n;
            if (k2 < k) k = k2;
        }
#pragma unroll
        for (int msk = 1; msk <= 32; msk <<= 1) {
            unsigned long long o = __shfl_xor(k, msk);
            if (o < k) k = o;
        }
        if (lane == 0) fb4[w] = k;
        __syncthreads();
        if (tid == 0) {
            unsigned long long m0 = fb4[0] < fb4[1] ? fb4[0] : fb4[1];
            unsigned long long m1 = fb4[2] < fb4[3] ? fb4[2] : fb4[3];
            rowbest[r] = (int)((m0 < m1 ? m0 : m1) & 0xFFFFFFFFu);
        }
        __syncthreads();
    }

    // ---- epilogue: gather z_q, STE, loss partial, index, histogram ----
    {
        const int row = tid >> 2, q = tid & 3;
        const size_t grow = (size_t)blk * BMR + row;
        const int bn = rowbest[row];
        const float4* zp4 = (const float4*)(zb + row * EDIM);
        const float4* ebr = (const float4*)(emb + (size_t)bn * EDIM);
        float4* outr = (float4*)(out + grow * EDIM);
        double lacc = 0.0;
#pragma unroll
        for (int i = 0; i < 16; ++i) {
            int k4 = q + i * 4;
            float4 zv = zp4[k4];
            float4 ev = ebr[k4];
            float4 o; float sd;
            sd = __fsub_rn(ev.x, zv.x); o.x = __fadd_rn(zv.x, sd); lacc += (double)__fmul_rn(sd, sd);
            sd = __fsub_rn(ev.y, zv.y); o.y = __fadd_rn(zv.y, sd); lacc += (double)__fmul_rn(sd, sd);
            sd = __fsub_rn(ev.z, zv.z); o.z = __fadd_rn(zv.z, sd); lacc += (double)__fmul_rn(sd, sd);
            sd = __fsub_rn(ev.w, zv.w); o.w = __fadd_rn(zv.w, sd); lacc += (double)__fmul_rn(sd, sd);
            outr[k4] = o;
        }
        if (q == 0) {
            out[OUT2 + grow] = (float)bn;
            atomicAdd(&count[bn], 1u);
        }
#pragma unroll
        for (int msk = 1; msk <= 32; msk <<= 1) lacc += __shfl_xor(lacc, msk);
        if (lane == 0) red4[w] = lacc;
        __syncthreads();
        if (tid == 0) atomicAdd(lossSum, red4[0] + red4[1] + red4[2] + red4[3]);
    }
}

__global__ void vq_finalize(const unsigned int* __restrict__ count,
                            const double* __restrict__ lossSum,
                            float* __restrict__ out)
{
    __shared__ double red[1024];
    int t = threadIdx.x;
    double em = (double)count[t] * (1.0 / 131072.0);
    red[t] = em * log(em + 1e-10);
    __syncthreads();
    for (int s = 512; s > 0; s >>= 1) {
        if (t < s) red[t] += red[t + s];
        __syncthreads();
    }
    if (t == 0) {
        out[OUT3] = (float)exp(-red[0]);
        double m = lossSum[0] * (1.0 / 33554432.0);
        out[OUT1] = (float)(1.25 * m);
    }
}

extern "C" void kernel_launch(void* const* d_in, const int* in_sizes, int n_in,
                              void* d_out, int out_size, void* d_ws, size_t ws_size,
                              hipStream_t stream) {
    const float* z   = (const float*)d_in[0];
    const float* emb = (const float*)d_in[1];
    float* out = (float*)d_out;

    unsigned short* emb16 = (unsigned short*)((char*)d_ws + WS_EMB16);
    float* esqg           = (float*)((char*)d_ws + WS_ESQ);
    unsigned int* count   = (unsigned int*)((char*)d_ws + WS_COUNT);
    double* lossSum       = (double*)((char*)d_ws + WS_LOSS);

    hipMemsetAsync((char*)d_ws + WS_COUNT, 0, 4104, stream);
    prep_emb<<<N_E, 64, 0, stream>>>(emb, emb16, esqg);
    vq_main<<<B_ROWS / BMR, 256, 0, stream>>>(z, emb, emb16, esqg, out, count, lossSum);
    vq_finalize<<<1, 1024, 0, stream>>>(count, lossSum, out);
}

// Round 7
// 14260.974 us; speedup vs baseline: 1.0214x; 1.0053x over previous
//
#include <hip/hip_runtime.h>

typedef __attribute__((ext_vector_type(8))) __bf16 bf16x8;
typedef __attribute__((ext_vector_type(4))) float f32x4;
typedef __attribute__((ext_vector_type(8))) unsigned short u16x8;

#define B_ROWS 131072
#define EDIM   256
#define N_E    1024
#define BMR    64          // rows per block
#define CHUNKS 32          // 32 chunks x 32 codes
#define CAP    8

#define OUT1 ((size_t)B_ROWS * EDIM)       // loss scalar
#define OUT2 (OUT1 + 1)                    // indices [B]
#define OUT3 (OUT2 + B_ROWS)               // perplexity scalar

// ws layout
#define WS_EMB16 0          // 1024*256 ushort = 524288 B (PRE-SWIZZLED rows)
#define WS_ESQ   524288     // 1024 float
#define WS_COUNT 528384     // 1024 uint
#define WS_LOSS  532480     // 1 double

__device__ __forceinline__ unsigned short f2bf(float f) {   // RN to bf16
    unsigned u = __float_as_uint(f);
    return (unsigned short)((u + 0x7FFFu + ((u >> 16) & 1u)) >> 16);
}
__device__ __forceinline__ unsigned encf(float f) {          // order-preserving
    unsigned u = __float_as_uint(f);
    return u ^ (unsigned)(((int)u >> 31) | 0x80000000);
}

// async global->LDS, 16B per lane (linear dest = wave-uniform base + lane*16)
__device__ __forceinline__ void gload16(const void* g, void* l) {
    __builtin_amdgcn_global_load_lds(
        (const __attribute__((address_space(1))) unsigned int*)g,
        (__attribute__((address_space(3))) unsigned int*)l, 16, 0, 0);
}

// numpy pairwise sum-of-squares over 128 elems (exact tree, no contraction)
__device__ inline float pw128_sq(const float* p) {
    float4 v0 = *(const float4*)p, v1 = *(const float4*)(p + 4);
    float r[8];
    r[0] = __fmul_rn(v0.x, v0.x); r[1] = __fmul_rn(v0.y, v0.y);
    r[2] = __fmul_rn(v0.z, v0.z); r[3] = __fmul_rn(v0.w, v0.w);
    r[4] = __fmul_rn(v1.x, v1.x); r[5] = __fmul_rn(v1.y, v1.y);
    r[6] = __fmul_rn(v1.z, v1.z); r[7] = __fmul_rn(v1.w, v1.w);
    for (int i = 8; i < 128; i += 8) {
        v0 = *(const float4*)(p + i); v1 = *(const float4*)(p + i + 4);
        r[0] = __fadd_rn(r[0], __fmul_rn(v0.x, v0.x));
        r[1] = __fadd_rn(r[1], __fmul_rn(v0.y, v0.y));
        r[2] = __fadd_rn(r[2], __fmul_rn(v0.z, v0.z));
        r[3] = __fadd_rn(r[3], __fmul_rn(v0.w, v0.w));
        r[4] = __fadd_rn(r[4], __fmul_rn(v1.x, v1.x));
        r[5] = __fadd_rn(r[5], __fmul_rn(v1.y, v1.y));
        r[6] = __fadd_rn(r[6], __fmul_rn(v1.z, v1.z));
        r[7] = __fadd_rn(r[7], __fmul_rn(v1.w, v1.w));
    }
    float s01 = __fadd_rn(r[0], r[1]), s23 = __fadd_rn(r[2], r[3]);
    float s45 = __fadd_rn(r[4], r[5]), s67 = __fadd_rn(r[6], r[7]);
    return __fadd_rn(__fadd_rn(s01, s23), __fadd_rn(s45, s67));
}

// exact fp32 distance, bit-identical to the verified rounds-1..6 chain
__device__ inline float exact_d(const float* zp, const float* ep, float zsq, float eq) {
    const float4* z4 = (const float4*)zp;
    const float4* e4 = (const float4*)ep;
    float acc = 0.f;
#pragma unroll 8
    for (int k = 0; k < 64; ++k) {
        float4 a = z4[k], b = e4[k];
        acc = __fmaf_rn(a.x, b.x, acc);
        acc = __fmaf_rn(a.y, b.y, acc);
        acc = __fmaf_rn(a.z, b.z, acc);
        acc = __fmaf_rn(a.w, b.w, acc);
    }
    return __fsub_rn(__fadd_rn(zsq, eq), 2.0f * acc);
}

// emb fp32 -> bf16 with rows stored PRE-SWIZZLED: granule g lands at g^(n&7)
__global__ void prep_emb(const float* __restrict__ emb,
                         unsigned short* __restrict__ emb16,
                         float* __restrict__ esqg)
{
    int n = blockIdx.x, t = threadIdx.x;          // 1024 blocks x 64 threads
    const float4 v = ((const float4*)(emb + (size_t)n * EDIM))[t];
    ushort4 o = { f2bf(v.x), f2bf(v.y), f2bf(v.z), f2bf(v.w) };
    int g = t >> 1, j0 = (t & 1) * 4;
    int didx = (((g ^ (n & 7)) << 3) + j0);
    *(ushort4*)(emb16 + (size_t)n * EDIM + didx) = o;
    if (t < 2) {
        float h = pw128_sq(emb + (size_t)n * EDIM + 128 * t);
        float ho = __shfl_xor(h, 1);
        if (t == 0) esqg[n] = __fadd_rn(h, ho);
    }
}

__global__ __launch_bounds__(256, 2) void vq_main(
    const float* __restrict__ z, const float* __restrict__ emb,
    const unsigned short* __restrict__ emb16, const float* __restrict__ esqg,
    float* __restrict__ out, unsigned int* __restrict__ count,
    double* __restrict__ lossSum)
{
    __shared__ unsigned short et[2][32 * EDIM];      // 2 x 16 KB (swizzled rows)
    __shared__ float esq_s[N_E];                     // 4 KB
    __shared__ float zsq_s[BMR], S_s[BMR];
    __shared__ float Mb[1];
    __shared__ unsigned cnt[BMR];
    __shared__ unsigned short list[BMR][CAP];        // 1 KB
    __shared__ int rowbest[BMR];
    __shared__ double red4[4];
    __shared__ unsigned long long fb4[4];

    const int tid  = threadIdx.x;
    const int blk  = blockIdx.x;
    const int lane = tid & 63;
    const int w    = tid >> 6;
    const int col  = lane & 15;
    const int quad = lane >> 4;
    const int nt   = w >> 1;       // code half (0/1)
    const int mh   = w & 1;        // row half (rows 32*mh..+32)

    const float* zb = z + (size_t)blk * BMR * EDIM;

    // ---- stage e chunk 0 (async, linear dest; source is pre-swizzled) ----
#pragma unroll
    for (int r2 = 0; r2 < 4; ++r2) {
        int G2 = r2 * 256 + tid;
        gload16(emb16 + (size_t)G2 * 8, &et[0][G2 * 8]);
    }
    for (int i = tid; i < N_E; i += 256) esq_s[i] = esqg[i];
    if (tid < BMR) cnt[tid] = 0u;

    // ---- A fragments from global z (one-time) ----
    bf16x8 afr[2][8];
#pragma unroll
    for (int mti = 0; mti < 2; ++mti) {
        int row = 32 * mh + 16 * mti + col;
#pragma unroll
        for (int ks = 0; ks < 8; ++ks) {
            const float* p = zb + row * EDIM + ((ks * 4 + quad) << 3);
            float4 a0 = *(const float4*)p;
            float4 a1 = *(const float4*)(p + 4);
            u16x8 t = { f2bf(a0.x), f2bf(a0.y), f2bf(a0.z), f2bf(a0.w),
                        f2bf(a1.x), f2bf(a1.y), f2bf(a1.z), f2bf(a1.w) };
            afr[mti][ks] = *(bf16x8*)&t;
        }
    }

    // ---- exact zsq (np-pairwise) + S = sum|z| (bound only) ----
    if (tid < 128) {
        int row = tid >> 1, half = tid & 1;
        const float* p = zb + row * EDIM + half * 128;
        float h = pw128_sq(p);
        const float4* p4 = (const float4*)p;
        float4 sv = {0.f, 0.f, 0.f, 0.f};
#pragma unroll
        for (int jj = 0; jj < 32; ++jj) {
            float4 vv = p4[jj];
            sv.x += fabsf(vv.x); sv.y += fabsf(vv.y);
            sv.z += fabsf(vv.z); sv.w += fabsf(vv.w);
        }
        float sa = (sv.x + sv.y) + (sv.z + sv.w);
        float ho = __shfl_xor(h, 1);
        float so = __shfl_xor(sa, 1);
        if (half == 0) {
            zsq_s[row] = __fadd_rn(h, ho);
            S_s[row]   = (sa + so) * 1.001f;
        }
    }
    __syncthreads();
    if (tid < 64) {                       // block margin M = S_max/65536 + 1e-4
        float v = S_s[tid];
#pragma unroll
        for (int m2 = 1; m2 <= 32; m2 <<= 1) v = fmaxf(v, __shfl_xor(v, m2));
        if (tid == 0) Mb[0] = v * (1.0f / 65536.0f) + 1e-4f;
    }
    __syncthreads();
    const float Mblk = Mb[0];

    const int erow  = nt * 16 + col;
    const int rowb0 = 32 * mh + 4 * quad;            // + 16*mti + r

    // ================= single-pass chunk loop =============================
    float bd[2][4]; int bc[2][4];
#pragma unroll
    for (int mti = 0; mti < 2; ++mti)
#pragma unroll
        for (int r = 0; r < 4; ++r) { bd[mti][r] = INFINITY; bc[mti][r] = 0; }

    for (int c = 0; c < CHUNKS; ++c) {
        if (c + 1 < CHUNKS) {            // async prefetch of next chunk -> LDS
#pragma unroll
            for (int r2 = 0; r2 < 4; ++r2) {
                int G2 = r2 * 256 + tid;
                gload16(emb16 + (size_t)(c + 1) * 32 * EDIM + (size_t)G2 * 8,
                        &et[(c + 1) & 1][G2 * 8]);
            }
        }
        const unsigned short* eb = &et[c & 1][0];
        f32x4 acc0 = {0.f, 0.f, 0.f, 0.f}, acc1 = {0.f, 0.f, 0.f, 0.f};
#pragma unroll
        for (int ks = 0; ks < 8; ++ks) {
            bf16x8 b = *(const bf16x8*)&eb[erow * EDIM + (((ks * 4 + quad) ^ (erow & 7)) << 3)];
            acc0 = __builtin_amdgcn_mfma_f32_16x16x32_bf16(afr[0][ks], b, acc0, 0, 0, 0);
            acc1 = __builtin_amdgcn_mfma_f32_16x16x32_bf16(afr[1][ks], b, acc1, 0, 0, 0);
        }
        const int codeN = c * 32 + erow;
        const float eqv = esq_s[codeN];
#pragma unroll
        for (int mti = 0; mti < 2; ++mti)
#pragma unroll
            for (int r = 0; r < 4; ++r) {
                float s   = __fmaf_rn(-2.0f, (mti ? acc1[r] : acc0[r]), eqv);
                float old = bd[mti][r];
                bool isnew = s < old;
                float ls = fmaxf(s, old);
                int   lc = isnew ? bc[mti][r] : codeN;
                bd[mti][r] = fminf(s, old);
                bc[mti][r] = isnew ? codeN : bc[mti][r];
                // sound gate: loser qualifies iff |s-old| <= M  (ls - bd_new <= M)
                if (__builtin_expect(fabsf(s - old) <= Mblk, 0)) {
                    int row = rowb0 + 16 * mti + r;
                    unsigned i = atomicAdd(&cnt[row], 1u);
                    if (i < CAP) list[row][i] = (unsigned short)lc;
                }
            }
        __syncthreads();
    }

    // ---- cross-col reduce per slot, push finals (2 per row: nt=0,1) ----
#pragma unroll
    for (int mti = 0; mti < 2; ++mti)
#pragma unroll
        for (int r = 0; r < 4; ++r) {
            unsigned long long kk =
                ((unsigned long long)encf(bd[mti][r]) << 32) | (unsigned)bc[mti][r];
#pragma unroll
            for (int msk = 1; msk <= 8; msk <<= 1) {
                unsigned long long o = __shfl_xor(kk, msk);
                if (o < kk) kk = o;
            }
            if (col == 0) {
                int row = rowb0 + 16 * mti + r;
                unsigned i = atomicAdd(&cnt[row], 1u);
                if (i < CAP) list[row][i] = (unsigned short)(kk & 0xFFFFu);
            }
        }
    __syncthreads();

    // ---- exact rescore of candidates (4 lanes / row, z from L2) ----
    {
        int row = tid >> 2, j = tid & 3;
        int cn = (int)cnt[row];
        unsigned long long bkey = ~0ull;
        float zq = zsq_s[row];
        const float* zrow = zb + row * EDIM;
        if (cn <= CAP) {
            for (int i = j; i < cn; i += 4) {
                int n = (int)list[row][i];
                float d = exact_d(zrow, emb + (size_t)n * EDIM, zq, esq_s[n]);
                unsigned long long k2 = ((unsigned long long)encf(d) << 32) | (unsigned)n;
                if (k2 < bkey) bkey = k2;
            }
        }
#pragma unroll
        for (int m = 1; m <= 2; m <<= 1) {
            unsigned long long o = __shfl_xor(bkey, m);
            if (o < bkey) bkey = o;
        }
        if (j == 0) rowbest[row] = (cn <= CAP) ? (int)(bkey & 0xFFFFFFFFu) : -1;
    }
    __syncthreads();

    // ---- overflow rows: full exact scan, block-cooperative (rare) ----
    for (int r = 0; r < BMR; ++r) {
        if (rowbest[r] != -1) continue;       // uniform branch
        const float* zr = zb + r * EDIM;
        float zqr = zsq_s[r];
        unsigned long long k = ~0ull;
        for (int ci = 0; ci < 4; ++ci) {
            int n = tid + ci * 256;
            float d = exact_d(zr, emb + (size_t)n * EDIM, zqr, esq_s[n]);
            unsigned long long k2 = ((unsigned long long)encf(d) << 32) | (unsigned)n;
            if (k2 < k) k = k2;
        }
#pragma unroll
        for (int msk = 1; msk <= 32; msk <<= 1) {
            unsigned long long o = __shfl_xor(k, msk);
            if (o < k) k = o;
        }
        if (lane == 0) fb4[w] = k;
        __syncthreads();
        if (tid == 0) {
            unsigned long long m0 = fb4[0] < fb4[1] ? fb4[0] : fb4[1];
            unsigned long long m1 = fb4[2] < fb4[3] ? fb4[2] : fb4[3];
            rowbest[r] = (int)((m0 < m1 ? m0 : m1) & 0xFFFFFFFFu);
        }
        __syncthreads();
    }

    // ---- epilogue: gather z_q, STE, loss partial, index, histogram ----
    {
        const int row = tid >> 2, q = tid & 3;
        const size_t grow = (size_t)blk * BMR + row;
        const int bn = rowbest[row];
        const float4* zp4 = (const float4*)(zb + row * EDIM);
        const float4* ebr = (const float4*)(emb + (size_t)bn * EDIM);
        float4* outr = (float4*)(out + grow * EDIM);
        double lacc = 0.0;
#pragma unroll
        for (int i = 0; i < 16; ++i) {
            int k4 = q + i * 4;
            float4 zv = zp4[k4];
            float4 ev = ebr[k4];
            float4 o; float sd;
            sd = __fsub_rn(ev.x, zv.x); o.x = __fadd_rn(zv.x, sd); lacc += (double)__fmul_rn(sd, sd);
            sd = __fsub_rn(ev.y, zv.y); o.y = __fadd_rn(zv.y, sd); lacc += (double)__fmul_rn(sd, sd);
            sd = __fsub_rn(ev.z, zv.z); o.z = __fadd_rn(zv.z, sd); lacc += (double)__fmul_rn(sd, sd);
            sd = __fsub_rn(ev.w, zv.w); o.w = __fadd_rn(zv.w, sd); lacc += (double)__fmul_rn(sd, sd);
            outr[k4] = o;
        }
        if (q == 0) {
            out[OUT2 + grow] = (float)bn;
            atomicAdd(&count[bn], 1u);
        }
#pragma unroll
        for (int msk = 1; msk <= 32; msk <<= 1) lacc += __shfl_xor(lacc, msk);
        if (lane == 0) red4[w] = lacc;
        __syncthreads();
        if (tid == 0) atomicAdd(lossSum, red4[0] + red4[1] + red4[2] + red4[3]);
    }
}

__global__ void vq_finalize(const unsigned int* __restrict__ count,
                            const double* __restrict__ lossSum,
                            float* __restrict__ out)
{
    __shared__ double red[1024];
    int t = threadIdx.x;
    double em = (double)count[t] * (1.0 / 131072.0);
    red[t] = em * log(em + 1e-10);
    __syncthreads();
    for (int s = 512; s > 0; s >>= 1) {
        if (t < s) red[t] += red[t + s];
        __syncthreads();
    }
    if (t == 0) {
        out[OUT3] = (float)exp(-red[0]);
        double m = lossSum[0] * (1.0 / 33554432.0);
        out[OUT1] = (float)(1.25 * m);
    }
}

extern "C" void kernel_launch(void* const* d_in, const int* in_sizes, int n_in,
                              void* d_out, int out_size, void* d_ws, size_t ws_size,
                              hipStream_t stream) {
    const float* z   = (const float*)d_in[0];
    const float* emb = (const float*)d_in[1];
    float* out = (float*)d_out;

    unsigned short* emb16 = (unsigned short*)((char*)d_ws + WS_EMB16);
    float* esqg           = (float*)((char*)d_ws + WS_ESQ);
    unsigned int* count   = (unsigned int*)((char*)d_ws + WS_COUNT);
    double* lossSum       = (double*)((char*)d_ws + WS_LOSS);

    hipMemsetAsync((char*)d_ws + WS_COUNT, 0, 4104, stream);
    prep_emb<<<N_E, 64, 0, stream>>>(emb, emb16, esqg);
    vq_main<<<B_ROWS / BMR, 256, 0, stream>>>(z, emb, emb16, esqg, out, count, lossSum);
    vq_finalize<<<1, 1024, 0, stream>>>(count, lossSum, out);
}

// Round 8
// 346.127 us; speedup vs baseline: 42.0848x; 41.2016x over previous
//
#include <hip/hip_runtime.h>

typedef __attribute__((ext_vector_type(8))) __bf16 bf16x8;
typedef __attribute__((ext_vector_type(4))) float f32x4;
typedef __attribute__((ext_vector_type(8))) unsigned short u16x8;

#define B_ROWS 131072
#define EDIM   256
#define N_E    1024
#define BMR    64          // rows per block
#define CHUNKS 32          // 32 chunks x 32 codes
#define CAP    16

#define OUT1 ((size_t)B_ROWS * EDIM)       // loss scalar
#define OUT2 (OUT1 + 1)                    // indices [B]
#define OUT3 (OUT2 + B_ROWS)               // perplexity scalar

// ws layout
#define WS_EMB16 0          // 1024*256 ushort = 524288 B (PRE-SWIZZLED rows)
#define WS_ESQ   524288     // 1024 float
#define WS_COUNT 528384     // 1024 uint
#define WS_LOSS  532480     // 1 double

__device__ __forceinline__ unsigned short f2bf(float f) {   // RN to bf16
    unsigned u = __float_as_uint(f);
    return (unsigned short)((u + 0x7FFFu + ((u >> 16) & 1u)) >> 16);
}
__device__ __forceinline__ unsigned encf(float f) {          // order-preserving
    unsigned u = __float_as_uint(f);
    return u ^ (unsigned)(((int)u >> 31) | 0x80000000);
}
__device__ __forceinline__ float decf(unsigned x) {
    return (x & 0x80000000u) ? __uint_as_float(x ^ 0x80000000u)
                             : __uint_as_float(~x);
}

// async global->LDS, 16B per lane (linear dest = wave-uniform base + lane*16)
__device__ __forceinline__ void gload16(const void* g, void* l) {
    __builtin_amdgcn_global_load_lds(
        (const __attribute__((address_space(1))) unsigned int*)g,
        (__attribute__((address_space(3))) unsigned int*)l, 16, 0, 0);
}

// numpy pairwise sum-of-squares over 128 elems (exact tree, no contraction)
__device__ inline float pw128_sq(const float* p) {
    float4 v0 = *(const float4*)p, v1 = *(const float4*)(p + 4);
    float r[8];
    r[0] = __fmul_rn(v0.x, v0.x); r[1] = __fmul_rn(v0.y, v0.y);
    r[2] = __fmul_rn(v0.z, v0.z); r[3] = __fmul_rn(v0.w, v0.w);
    r[4] = __fmul_rn(v1.x, v1.x); r[5] = __fmul_rn(v1.y, v1.y);
    r[6] = __fmul_rn(v1.z, v1.z); r[7] = __fmul_rn(v1.w, v1.w);
    for (int i = 8; i < 128; i += 8) {
        v0 = *(const float4*)(p + i); v1 = *(const float4*)(p + i + 4);
        r[0] = __fadd_rn(r[0], __fmul_rn(v0.x, v0.x));
        r[1] = __fadd_rn(r[1], __fmul_rn(v0.y, v0.y));
        r[2] = __fadd_rn(r[2], __fmul_rn(v0.z, v0.z));
        r[3] = __fadd_rn(r[3], __fmul_rn(v0.w, v0.w));
        r[4] = __fadd_rn(r[4], __fmul_rn(v1.x, v1.x));
        r[5] = __fadd_rn(r[5], __fmul_rn(v1.y, v1.y));
        r[6] = __fadd_rn(r[6], __fmul_rn(v1.z, v1.z));
        r[7] = __fadd_rn(r[7], __fmul_rn(v1.w, v1.w));
    }
    float s01 = __fadd_rn(r[0], r[1]), s23 = __fadd_rn(r[2], r[3]);
    float s45 = __fadd_rn(r[4], r[5]), s67 = __fadd_rn(r[6], r[7]);
    return __fadd_rn(__fadd_rn(s01, s23), __fadd_rn(s45, s67));
}

// exact fp32 distance, bit-identical to the verified rounds-1..7 chain
__device__ inline float exact_d(const float* zp, const float* ep, float zsq, float eq) {
    const float4* z4 = (const float4*)zp;
    const float4* e4 = (const float4*)ep;
    float acc = 0.f;
#pragma unroll 8
    for (int k = 0; k < 64; ++k) {
        float4 a = z4[k], b = e4[k];
        acc = __fmaf_rn(a.x, b.x, acc);
        acc = __fmaf_rn(a.y, b.y, acc);
        acc = __fmaf_rn(a.z, b.z, acc);
        acc = __fmaf_rn(a.w, b.w, acc);
    }
    return __fsub_rn(__fadd_rn(zsq, eq), 2.0f * acc);
}

// emb fp32 -> bf16 with rows stored PRE-SWIZZLED: granule g lands at g^(n&7)
__global__ void prep_emb(const float* __restrict__ emb,
                         unsigned short* __restrict__ emb16,
                         float* __restrict__ esqg)
{
    int n = blockIdx.x, t = threadIdx.x;          // 1024 blocks x 64 threads
    const float4 v = ((const float4*)(emb + (size_t)n * EDIM))[t];
    ushort4 o = { f2bf(v.x), f2bf(v.y), f2bf(v.z), f2bf(v.w) };
    int g = t >> 1, j0 = (t & 1) * 4;
    int didx = (((g ^ (n & 7)) << 3) + j0);
    *(ushort4*)(emb16 + (size_t)n * EDIM + didx) = o;
    if (t < 2) {
        float h = pw128_sq(emb + (size_t)n * EDIM + 128 * t);
        float ho = __shfl_xor(h, 1);
        if (t == 0) esqg[n] = __fadd_rn(h, ho);
    }
}

__global__ __launch_bounds__(256, 2) void vq_main(
    const float* __restrict__ z, const float* __restrict__ emb,
    const unsigned short* __restrict__ emb16, const float* __restrict__ esqg,
    float* __restrict__ out, unsigned int* __restrict__ count,
    double* __restrict__ lossSum)
{
    __shared__ unsigned short et[2][32 * EDIM];      // 2 x 16 KB (swizzled rows)
    __shared__ float esq_s[N_E];                     // 4 KB
    __shared__ float zsq_s[BMR], S_s[BMR], thr_s[BMR];
    __shared__ unsigned long long wd64[2][BMR];      // 1 KB
    __shared__ unsigned cnt[BMR];
    __shared__ unsigned short list[BMR][CAP];        // 2 KB
    __shared__ int rowbest[BMR];
    __shared__ double red4[4];
    __shared__ unsigned long long fb4[4];

    const int tid  = threadIdx.x;
    const int blk  = blockIdx.x;
    const int lane = tid & 63;
    const int w    = tid >> 6;
    const int col  = lane & 15;
    const int quad = lane >> 4;
    const int nt   = w >> 1;       // code half (0/1)
    const int mh   = w & 1;        // row half (rows 32*mh..+32)

    const float* zb = z + (size_t)blk * BMR * EDIM;

    // ---- stage e chunk 0 (async, linear dest; source is pre-swizzled) ----
#pragma unroll
    for (int r2 = 0; r2 < 4; ++r2) {
        int G2 = r2 * 256 + tid;
        gload16(emb16 + (size_t)G2 * 8, &et[0][G2 * 8]);
    }
    for (int i = tid; i < N_E; i += 256) esq_s[i] = esqg[i];
    if (tid < BMR) cnt[tid] = 0u;

    // ---- A fragments from global z (one-time) ----
    bf16x8 afr[2][8];
#pragma unroll
    for (int mti = 0; mti < 2; ++mti) {
        int row = 32 * mh + 16 * mti + col;
#pragma unroll
        for (int ks = 0; ks < 8; ++ks) {
            const float* p = zb + row * EDIM + ((ks * 4 + quad) << 3);
            float4 a0 = *(const float4*)p;
            float4 a1 = *(const float4*)(p + 4);
            u16x8 t = { f2bf(a0.x), f2bf(a0.y), f2bf(a0.z), f2bf(a0.w),
                        f2bf(a1.x), f2bf(a1.y), f2bf(a1.z), f2bf(a1.w) };
            afr[mti][ks] = *(bf16x8*)&t;
        }
    }

    // ---- exact zsq (np-pairwise) + S = sum|z| (bound only) ----
    if (tid < 128) {
        int row = tid >> 1, half = tid & 1;
        const float* p = zb + row * EDIM + half * 128;
        float h = pw128_sq(p);
        const float4* p4 = (const float4*)p;
        float4 sv = {0.f, 0.f, 0.f, 0.f};
#pragma unroll
        for (int jj = 0; jj < 32; ++jj) {
            float4 vv = p4[jj];
            sv.x += fabsf(vv.x); sv.y += fabsf(vv.y);
            sv.z += fabsf(vv.z); sv.w += fabsf(vv.w);
        }
        float sa = (sv.x + sv.y) + (sv.z + sv.w);
        float ho = __shfl_xor(h, 1);
        float so = __shfl_xor(sa, 1);
        if (half == 0) {
            zsq_s[row] = __fadd_rn(h, ho);
            S_s[row]   = (sa + so) * 1.001f;
        }
    }
    __syncthreads();

    const int erow  = nt * 16 + col;
    const int rowb0 = 32 * mh + 4 * quad;            // + 16*mti + r

    // ================= PASS A: scores + register-only running min ==========
    float bd[2][4]; int bc[2][4];
#pragma unroll
    for (int mti = 0; mti < 2; ++mti)
#pragma unroll
        for (int r = 0; r < 4; ++r) { bd[mti][r] = INFINITY; bc[mti][r] = 0; }

    for (int c = 0; c < CHUNKS; ++c) {
        if (c + 1 < CHUNKS) {            // async prefetch of next chunk -> LDS
#pragma unroll
            for (int r2 = 0; r2 < 4; ++r2) {
                int G2 = r2 * 256 + tid;
                gload16(emb16 + (size_t)(c + 1) * 32 * EDIM + (size_t)G2 * 8,
                        &et[(c + 1) & 1][G2 * 8]);
            }
        }
        const unsigned short* eb = &et[c & 1][0];
        f32x4 acc0 = {0.f, 0.f, 0.f, 0.f}, acc1 = {0.f, 0.f, 0.f, 0.f};
#pragma unroll
        for (int ks = 0; ks < 8; ++ks) {
            bf16x8 b = *(const bf16x8*)&eb[erow * EDIM + (((ks * 4 + quad) ^ (erow & 7)) << 3)];
            acc0 = __builtin_amdgcn_mfma_f32_16x16x32_bf16(afr[0][ks], b, acc0, 0, 0, 0);
            acc1 = __builtin_amdgcn_mfma_f32_16x16x32_bf16(afr[1][ks], b, acc1, 0, 0, 0);
        }
        const int codeN = c * 32 + erow;
        const float eqv = esq_s[codeN];
#pragma unroll
        for (int r = 0; r < 4; ++r) {
            float s0 = __fmaf_rn(-2.0f, acc0[r], eqv);
            float s1 = __fmaf_rn(-2.0f, acc1[r], eqv);
            if (s0 < bd[0][r]) { bd[0][r] = s0; bc[0][r] = codeN; }
            if (s1 < bd[1][r]) { bd[1][r] = s1; bc[1][r] = codeN; }
        }
        __syncthreads();
    }

    // restage chunk 0 for pass B (drained by the barrier below)
#pragma unroll
    for (int r2 = 0; r2 < 4; ++r2) {
        int G2 = r2 * 256 + tid;
        gload16(emb16 + (size_t)G2 * 8, &et[0][G2 * 8]);
    }

    // ---- one-time cross-col reduce (lex min on (score, code)) ----
#pragma unroll
    for (int mti = 0; mti < 2; ++mti)
#pragma unroll
        for (int r = 0; r < 4; ++r) {
            unsigned long long kk =
                ((unsigned long long)encf(bd[mti][r]) << 32) | (unsigned)bc[mti][r];
#pragma unroll
            for (int msk = 1; msk <= 8; msk <<= 1) {
                unsigned long long o = __shfl_xor(kk, msk);
                if (o < kk) kk = o;
            }
            if (col == 0) wd64[nt][rowb0 + 16 * mti + r] = kk;
        }
    __syncthreads();
    if (tid < BMR) {
        unsigned long long a = wd64[0][tid], b = wd64[1][tid];
        unsigned long long mn = a < b ? a : b;
        thr_s[tid] = decf((unsigned)(mn >> 32)) + (S_s[tid] * (1.0f / 131072.0f) + 1e-4f);
    }
    __syncthreads();

    float thrM[2][4];
#pragma unroll
    for (int mti = 0; mti < 2; ++mti)
#pragma unroll
        for (int r = 0; r < 4; ++r)
            thrM[mti][r] = thr_s[rowb0 + 16 * mti + r];

    // ================= PASS B: recompute scores, gather candidates =========
    for (int c = 0; c < CHUNKS; ++c) {
        if (c + 1 < CHUNKS) {
#pragma unroll
            for (int r2 = 0; r2 < 4; ++r2) {
                int G2 = r2 * 256 + tid;
                gload16(emb16 + (size_t)(c + 1) * 32 * EDIM + (size_t)G2 * 8,
                        &et[(c + 1) & 1][G2 * 8]);
            }
        }
        const unsigned short* eb = &et[c & 1][0];
        f32x4 acc0 = {0.f, 0.f, 0.f, 0.f}, acc1 = {0.f, 0.f, 0.f, 0.f};
#pragma unroll
        for (int ks = 0; ks < 8; ++ks) {
            bf16x8 b = *(const bf16x8*)&eb[erow * EDIM + (((ks * 4 + quad) ^ (erow & 7)) << 3)];
            acc0 = __builtin_amdgcn_mfma_f32_16x16x32_bf16(afr[0][ks], b, acc0, 0, 0, 0);
            acc1 = __builtin_amdgcn_mfma_f32_16x16x32_bf16(afr[1][ks], b, acc1, 0, 0, 0);
        }
        const int codeN = c * 32 + erow;
        const float eqv = esq_s[codeN];
#pragma unroll
        for (int r = 0; r < 4; ++r) {
            float s0 = __fmaf_rn(-2.0f, acc0[r], eqv);
            float s1 = __fmaf_rn(-2.0f, acc1[r], eqv);
            if (__builtin_expect(s0 <= thrM[0][r], 0)) {
                int row = rowb0 + r;
                unsigned i = atomicAdd(&cnt[row], 1u);
                if (i < CAP) list[row][i] = (unsigned short)codeN;
            }
            if (__builtin_expect(s1 <= thrM[1][r], 0)) {
                int row = rowb0 + 16 + r;
                unsigned i = atomicAdd(&cnt[row], 1u);
                if (i < CAP) list[row][i] = (unsigned short)codeN;
            }
        }
        __syncthreads();
    }

    // ---- exact rescore of candidates (4 lanes / row, z from L2) ----
    {
        int row = tid >> 2, j = tid & 3;
        int cn = (int)cnt[row];
        unsigned long long bkey = ~0ull;
        float zq = zsq_s[row];
        const float* zrow = zb + row * EDIM;
        if (cn <= CAP) {
            for (int i = j; i < cn; i += 4) {
                int n = (int)list[row][i];
                float d = exact_d(zrow, emb + (size_t)n * EDIM, zq, esq_s[n]);
                unsigned long long k2 = ((unsigned long long)encf(d) << 32) | (unsigned)n;
                if (k2 < bkey) bkey = k2;
            }
        }
#pragma unroll
        for (int m = 1; m <= 2; m <<= 1) {
            unsigned long long o = __shfl_xor(bkey, m);
            if (o < bkey) bkey = o;
        }
        if (j == 0) rowbest[row] = (cn <= CAP) ? (int)(bkey & 0xFFFFFFFFu) : -1;
    }
    __syncthreads();

    // ---- overflow rows: full exact scan, block-cooperative (rare) ----
    for (int r = 0; r < BMR; ++r) {
        if (rowbest[r] != -1) continue;       // uniform branch
        const float* zr = zb + r * EDIM;
        float zqr = zsq_s[r];
        unsigned long long k = ~0ull;
        for (int ci = 0; ci < 4; ++ci) {
            int n = tid + ci * 256;
            float d = exact_d(zr, emb + (size_t)n * EDIM, zqr, esq_s[n]);
            unsigned long long k2 = ((unsigned long long)encf(d) << 32) | (unsigned)n;
            if (k2 < k) k = k2;
        }
#pragma unroll
        for (int msk = 1; msk <= 32; msk <<= 1) {
            unsigned long long o = __shfl_xor(k, msk);
            if (o < k) k = o;
        }
        if (lane == 0) fb4[w] = k;
        __syncthreads();
        if (tid == 0) {
            unsigned long long m0 = fb4[0] < fb4[1] ? fb4[0] : fb4[1];
            unsigned long long m1 = fb4[2] < fb4[3] ? fb4[2] : fb4[3];
            rowbest[r] = (int)((m0 < m1 ? m0 : m1) & 0xFFFFFFFFu);
        }
        __syncthreads();
    }

    // ---- epilogue: gather z_q, STE, loss partial, index, histogram ----
    {
        const int row = tid >> 2, q = tid & 3;
        const size_t grow = (size_t)blk * BMR + row;
        const int bn = rowbest[row];
        const float4* zp4 = (const float4*)(zb + row * EDIM);
        const float4* ebr = (const float4*)(emb + (size_t)bn * EDIM);
        float4* outr = (float4*)(out + grow * EDIM);
        double lacc = 0.0;
#pragma unroll
        for (int i = 0; i < 16; ++i) {
            int k4 = q + i * 4;
            float4 zv = zp4[k4];
            float4 ev = ebr[k4];
            float4 o; float sd;
            sd = __fsub_rn(ev.x, zv.x); o.x = __fadd_rn(zv.x, sd); lacc += (double)__fmul_rn(sd, sd);
            sd = __fsub_rn(ev.y, zv.y); o.y = __fadd_rn(zv.y, sd); lacc += (double)__fmul_rn(sd, sd);
            sd = __fsub_rn(ev.z, zv.z); o.z = __fadd_rn(zv.z, sd); lacc += (double)__fmul_rn(sd, sd);
            sd = __fsub_rn(ev.w, zv.w); o.w = __fadd_rn(zv.w, sd); lacc += (double)__fmul_rn(sd, sd);
            outr[k4] = o;
        }
        if (q == 0) {
            out[OUT2 + grow] = (float)bn;
            atomicAdd(&count[bn], 1u);
        }
#pragma unroll
        for (int msk = 1; msk <= 32; msk <<= 1) lacc += __shfl_xor(lacc, msk);
        if (lane == 0) red4[w] = lacc;
        __syncthreads();
        if (tid == 0) atomicAdd(lossSum, red4[0] + red4[1] + red4[2] + red4[3]);
    }
}

__global__ void vq_finalize(const unsigned int* __restrict__ count,
                            const double* __restrict__ lossSum,
                            float* __restrict__ out)
{
    __shared__ double red[1024];
    int t = threadIdx.x;
    double em = (double)count[t] * (1.0 / 131072.0);
    red[t] = em * log(em + 1e-10);
    __syncthreads();
    for (int s = 512; s > 0; s >>= 1) {
        if (t < s) red[t] += red[t + s];
        __syncthreads();
    }
    if (t == 0) {
        out[OUT3] = (float)exp(-red[0]);
        double m = lossSum[0] * (1.0 / 33554432.0);
        out[OUT1] = (float)(1.25 * m);
    }
}

extern "C" void kernel_launch(void* const* d_in, const int* in_sizes, int n_in,
                              void* d_out, int out_size, void* d_ws, size_t ws_size,
                              hipStream_t stream) {
    const float* z   = (const float*)d_in[0];
    const float* emb = (const float*)d_in[1];
    float* out = (float*)d_out;

    unsigned short* emb16 = (unsigned short*)((char*)d_ws + WS_EMB16);
    float* esqg           = (float*)((char*)d_ws + WS_ESQ);
    unsigned int* count   = (unsigned int*)((char*)d_ws + WS_COUNT);
    double* lossSum       = (double*)((char*)d_ws + WS_LOSS);

    hipMemsetAsync((char*)d_ws + WS_COUNT, 0, 4104, stream);
    prep_emb<<<N_E, 64, 0, stream>>>(emb, emb16, esqg);
    vq_main<<<B_ROWS / BMR, 256, 0, stream>>>(z, emb, emb16, esqg, out, count, lossSum);
    vq_finalize<<<1, 1024, 0, stream>>>(count, lossSum, out);
}

// Round 9
// 345.874 us; speedup vs baseline: 42.1155x; 1.0007x over previous
//
#include <hip/hip_runtime.h>

typedef __attribute__((ext_vector_type(8))) __bf16 bf16x8;
typedef __attribute__((ext_vector_type(4))) float f32x4;
typedef __attribute__((ext_vector_type(8))) unsigned short u16x8;

#define B_ROWS 131072
#define EDIM   256
#define N_E    1024
#define BMR    64          // rows per block
#define CHUNKS 32          // 32 chunks x 32 codes (16 per nt-half)
#define CAP    16

#define OUT1 ((size_t)B_ROWS * EDIM)       // loss scalar
#define OUT2 (OUT1 + 1)                    // indices [B]
#define OUT3 (OUT2 + B_ROWS)               // perplexity scalar

// ws layout
#define WS_EMBT  0          // emb16T: [32 granules][1024 codes][8 bf16] = 524288 B
#define WS_ESQ   524288     // 1024 float
#define WS_COUNT 528384     // 1024 uint
#define WS_LOSS  532480     // 1 double

__device__ __forceinline__ unsigned short f2bf(float f) {   // RN to bf16
    unsigned u = __float_as_uint(f);
    return (unsigned short)((u + 0x7FFFu + ((u >> 16) & 1u)) >> 16);
}
__device__ __forceinline__ unsigned encf(float f) {          // order-preserving
    unsigned u = __float_as_uint(f);
    return u ^ (unsigned)(((int)u >> 31) | 0x80000000);
}
__device__ __forceinline__ float decf(unsigned x) {
    return (x & 0x80000000u) ? __uint_as_float(x ^ 0x80000000u)
                             : __uint_as_float(~x);
}
__device__ __forceinline__ float med3f(float a, float b, float c) {
#if __has_builtin(__builtin_amdgcn_fmed3f)
    return __builtin_amdgcn_fmed3f(a, b, c);
#else
    return fmaxf(fminf(a, b), fminf(fmaxf(a, b), c));
#endif
}

// numpy pairwise sum-of-squares over 128 elems (exact tree, no contraction)
__device__ inline float pw128_sq(const float* p) {
    float4 v0 = *(const float4*)p, v1 = *(const float4*)(p + 4);
    float r[8];
    r[0] = __fmul_rn(v0.x, v0.x); r[1] = __fmul_rn(v0.y, v0.y);
    r[2] = __fmul_rn(v0.z, v0.z); r[3] = __fmul_rn(v0.w, v0.w);
    r[4] = __fmul_rn(v1.x, v1.x); r[5] = __fmul_rn(v1.y, v1.y);
    r[6] = __fmul_rn(v1.z, v1.z); r[7] = __fmul_rn(v1.w, v1.w);
    for (int i = 8; i < 128; i += 8) {
        v0 = *(const float4*)(p + i); v1 = *(const float4*)(p + i + 4);
        r[0] = __fadd_rn(r[0], __fmul_rn(v0.x, v0.x));
        r[1] = __fadd_rn(r[1], __fmul_rn(v0.y, v0.y));
        r[2] = __fadd_rn(r[2], __fmul_rn(v0.z, v0.z));
        r[3] = __fadd_rn(r[3], __fmul_rn(v0.w, v0.w));
        r[4] = __fadd_rn(r[4], __fmul_rn(v1.x, v1.x));
        r[5] = __fadd_rn(r[5], __fmul_rn(v1.y, v1.y));
        r[6] = __fadd_rn(r[6], __fmul_rn(v1.z, v1.z));
        r[7] = __fadd_rn(r[7], __fmul_rn(v1.w, v1.w));
    }
    float s01 = __fadd_rn(r[0], r[1]), s23 = __fadd_rn(r[2], r[3]);
    float s45 = __fadd_rn(r[4], r[5]), s67 = __fadd_rn(r[6], r[7]);
    return __fadd_rn(__fadd_rn(s01, s23), __fadd_rn(s45, s67));
}

// exact fp32 distance, bit-identical to the verified rounds-1..8 chain
__device__ inline float exact_d(const float* zp, const float* ep, float zsq, float eq) {
    const float4* z4 = (const float4*)zp;
    const float4* e4 = (const float4*)ep;
    float acc = 0.f;
#pragma unroll 8
    for (int k = 0; k < 64; ++k) {
        float4 a = z4[k], b = e4[k];
        acc = __fmaf_rn(a.x, b.x, acc);
        acc = __fmaf_rn(a.y, b.y, acc);
        acc = __fmaf_rn(a.z, b.z, acc);
        acc = __fmaf_rn(a.w, b.w, acc);
    }
    return __fsub_rn(__fadd_rn(zsq, eq), 2.0f * acc);
}

// emb fp32 -> bf16, TRANSPOSED layout: embT[g][n] = 16B granule g of code n
__global__ void prep_emb(const float* __restrict__ emb,
                         unsigned short* __restrict__ embT,
                         float* __restrict__ esqg)
{
    int n = blockIdx.x, t = threadIdx.x;          // 1024 blocks x 64 threads
    const float4 v = ((const float4*)(emb + (size_t)n * EDIM))[t];
    ushort4 o = { f2bf(v.x), f2bf(v.y), f2bf(v.z), f2bf(v.w) };
    int g = t >> 1, j0 = (t & 1) * 4;
    *(ushort4*)(embT + ((size_t)g * N_E + n) * 8 + j0) = o;
    if (t < 2) {
        float h = pw128_sq(emb + (size_t)n * EDIM + 128 * t);
        float ho = __shfl_xor(h, 1);
        if (t == 0) esqg[n] = __fadd_rn(h, ho);
    }
}

__global__ __launch_bounds__(256, 2) void vq_main(
    const float* __restrict__ z, const float* __restrict__ emb,
    const unsigned short* __restrict__ embT, const float* __restrict__ esqg,
    float* __restrict__ out, unsigned int* __restrict__ count,
    double* __restrict__ lossSum)
{
    __shared__ float esq_s[N_E];                     // 4 KB
    __shared__ float zsq_s[BMR], S_s[BMR], thr_s[BMR];
    __shared__ unsigned long long wd64[2][BMR];      // 1 KB
    __shared__ unsigned cnt[BMR];
    __shared__ unsigned short list[BMR][CAP];        // 2 KB
    __shared__ int rowbest[BMR];
    __shared__ double red4[4];
    __shared__ unsigned long long fb4[4];

    const int tid  = threadIdx.x;
    const int blk  = blockIdx.x;
    const int lane = tid & 63;
    const int w    = tid >> 6;
    const int col  = lane & 15;
    const int quad = lane >> 4;
    const int nt   = w >> 1;       // code half within each 32-code chunk
    const int mh   = w & 1;        // row half (rows 32*mh..+32)

    const float* zb = z + (size_t)blk * BMR * EDIM;

    for (int i = tid; i < N_E; i += 256) esq_s[i] = esqg[i];
    if (tid < BMR) cnt[tid] = 0u;

    // ---- A fragments from global z (one-time) ----
    bf16x8 afr[2][8];
#pragma unroll
    for (int mti = 0; mti < 2; ++mti) {
        int row = 32 * mh + 16 * mti + col;
#pragma unroll
        for (int ks = 0; ks < 8; ++ks) {
            const float* p = zb + row * EDIM + ((ks * 4 + quad) << 3);
            float4 a0 = *(const float4*)p;
            float4 a1 = *(const float4*)(p + 4);
            u16x8 t = { f2bf(a0.x), f2bf(a0.y), f2bf(a0.z), f2bf(a0.w),
                        f2bf(a1.x), f2bf(a1.y), f2bf(a1.z), f2bf(a1.w) };
            afr[mti][ks] = *(bf16x8*)&t;
        }
    }

    // ---- exact zsq (np-pairwise) + S = sum|z| (bound only) ----
    if (tid < 128) {
        int row = tid >> 1, half = tid & 1;
        const float* p = zb + row * EDIM + half * 128;
        float h = pw128_sq(p);
        const float4* p4 = (const float4*)p;
        float4 sv = {0.f, 0.f, 0.f, 0.f};
#pragma unroll
        for (int jj = 0; jj < 32; ++jj) {
            float4 vv = p4[jj];
            sv.x += fabsf(vv.x); sv.y += fabsf(vv.y);
            sv.z += fabsf(vv.z); sv.w += fabsf(vv.w);
        }
        float sa = (sv.x + sv.y) + (sv.z + sv.w);
        float ho = __shfl_xor(h, 1);
        float so = __shfl_xor(sa, 1);
        if (half == 0) {
            zsq_s[row] = __fadd_rn(h, ho);
            S_s[row]   = (sa + so) * 1.001f;
        }
    }
    __syncthreads();

    // per-lane constant voffsets for the 8 B-granule loads (shorts)
    int koff[8];
#pragma unroll
    for (int ks = 0; ks < 8; ++ks)
        koff[ks] = (((ks * 4 + quad) << 10) + nt * 16 + col) * 8;

    // ================= barrier-free single-pass chunk loop =================
    float bd1[2][4], bd2[2][4], bd3[2][4];
    int   c1_[2][4], c2_[2][4];
#pragma unroll
    for (int mti = 0; mti < 2; ++mti)
#pragma unroll
        for (int r = 0; r < 4; ++r) {
            bd1[mti][r] = INFINITY; bd2[mti][r] = INFINITY; bd3[mti][r] = INFINITY;
            c1_[mti][r] = 0; c2_[mti][r] = 0;
        }

#pragma unroll 4
    for (int c = 0; c < CHUNKS; ++c) {
        const unsigned short* cb = embT + (c << 8);      // +c*32 codes (uniform)
        u16x8 bfr[8];
#pragma unroll
        for (int ks = 0; ks < 8; ++ks)
            bfr[ks] = *(const u16x8*)(cb + koff[ks]);
        f32x4 acc0 = {0.f, 0.f, 0.f, 0.f}, acc1 = {0.f, 0.f, 0.f, 0.f};
#pragma unroll
        for (int ks = 0; ks < 8; ++ks) {
            bf16x8 b = *(bf16x8*)&bfr[ks];
            acc0 = __builtin_amdgcn_mfma_f32_16x16x32_bf16(afr[0][ks], b, acc0, 0, 0, 0);
            acc1 = __builtin_amdgcn_mfma_f32_16x16x32_bf16(afr[1][ks], b, acc1, 0, 0, 0);
        }
        const int codeN = (c << 5) + nt * 16 + col;
        const float eqv = esq_s[codeN];
#pragma unroll
        for (int mti = 0; mti < 2; ++mti)
#pragma unroll
            for (int r = 0; r < 4; ++r) {
                float s = __fmaf_rn(-2.0f, (mti ? acc1[r] : acc0[r]), eqv);
                bool lt1 = s < bd1[mti][r];
                bool lt2 = s < bd2[mti][r];
                bd3[mti][r] = med3f(s, bd2[mti][r], bd3[mti][r]);
                bd2[mti][r] = med3f(s, bd1[mti][r], bd2[mti][r]);
                c2_[mti][r] = lt1 ? c1_[mti][r] : (lt2 ? codeN : c2_[mti][r]);
                bd1[mti][r] = fminf(s, bd1[mti][r]);
                c1_[mti][r] = lt1 ? codeN : c1_[mti][r];
            }
    }

    // ---- cross-col reduce of bd1 (lex min on (score, code)) ----
#pragma unroll
    for (int mti = 0; mti < 2; ++mti)
#pragma unroll
        for (int r = 0; r < 4; ++r) {
            unsigned long long kk =
                ((unsigned long long)encf(bd1[mti][r]) << 32) | (unsigned)c1_[mti][r];
#pragma unroll
            for (int msk = 1; msk <= 8; msk <<= 1) {
                unsigned long long o = __shfl_xor(kk, msk);
                if (o < kk) kk = o;
            }
            if (col == 0) wd64[nt][32 * mh + 16 * mti + 4 * quad + r] = kk;
        }
    __syncthreads();
    if (tid < BMR) {
        unsigned long long a = wd64[0][tid], b = wd64[1][tid];
        unsigned long long mn = a < b ? a : b;
        thr_s[tid] = decf((unsigned)(mn >> 32)) + (S_s[tid] * (1.0f / 131072.0f) + 1e-4f);
    }
    __syncthreads();

    // ---- candidate push + overflow flag (top-3 soundness) ----
#pragma unroll
    for (int mti = 0; mti < 2; ++mti)
#pragma unroll
        for (int r = 0; r < 4; ++r) {
            int row = 32 * mh + 16 * mti + 4 * quad + r;
            float th = thr_s[row];
            if (__builtin_expect(bd1[mti][r] <= th, 0)) {
                unsigned i = atomicAdd(&cnt[row], 1u);
                if (i < CAP) list[row][i] = (unsigned short)c1_[mti][r];
            }
            if (__builtin_expect(bd2[mti][r] <= th, 0)) {
                unsigned i = atomicAdd(&cnt[row], 1u);
                if (i < CAP) list[row][i] = (unsigned short)c2_[mti][r];
            }
            if (__builtin_expect(bd3[mti][r] <= th, 0))
                atomicAdd(&cnt[row], 1000u);     // may have dropped a candidate
        }
    __syncthreads();

    // ---- exact rescore of candidates (4 lanes / row, z from L2) ----
    {
        int row = tid >> 2, j = tid & 3;
        int cn = (int)cnt[row];
        unsigned long long bkey = ~0ull;
        float zq = zsq_s[row];
        const float* zrow = zb + row * EDIM;
        if (cn <= CAP) {
            for (int i = j; i < cn; i += 4) {
                int n = (int)list[row][i];
                float d = exact_d(zrow, emb + (size_t)n * EDIM, zq, esq_s[n]);
                unsigned long long k2 = ((unsigned long long)encf(d) << 32) | (unsigned)n;
                if (k2 < bkey) bkey = k2;
            }
        }
#pragma unroll
        for (int m = 1; m <= 2; m <<= 1) {
            unsigned long long o = __shfl_xor(bkey, m);
            if (o < bkey) bkey = o;
        }
        if (j == 0) rowbest[row] = (cn <= CAP) ? (int)(bkey & 0xFFFFFFFFu) : -1;
    }
    __syncthreads();

    // ---- overflow rows: full exact scan, block-cooperative (rare) ----
    for (int r = 0; r < BMR; ++r) {
        if (rowbest[r] != -1) continue;       // uniform branch
        const float* zr = zb + r * EDIM;
        float zqr = zsq_s[r];
        unsigned long long k = ~0ull;
        for (int ci = 0; ci < 4; ++ci) {
            int n = tid + ci * 256;
            float d = exact_d(zr, emb + (size_t)n * EDIM, zqr, esq_s[n]);
            unsigned long long k2 = ((unsigned long long)encf(d) << 32) | (unsigned)n;
            if (k2 < k) k = k2;
        }
#pragma unroll
        for (int msk = 1; msk <= 32; msk <<= 1) {
            unsigned long long o = __shfl_xor(k, msk);
            if (o < k) k = o;
        }
        if (lane == 0) fb4[w] = k;
        __syncthreads();
        if (tid == 0) {
            unsigned long long m0 = fb4[0] < fb4[1] ? fb4[0] : fb4[1];
            unsigned long long m1 = fb4[2] < fb4[3] ? fb4[2] : fb4[3];
            rowbest[r] = (int)((m0 < m1 ? m0 : m1) & 0xFFFFFFFFu);
        }
        __syncthreads();
    }

    // ---- epilogue: gather z_q, STE, loss partial, index, histogram ----
    {
        const int row = tid >> 2, q = tid & 3;
        const size_t grow = (size_t)blk * BMR + row;
        const int bn = rowbest[row];
        const float4* zp4 = (const float4*)(zb + row * EDIM);
        const float4* ebr = (const float4*)(emb + (size_t)bn * EDIM);
        float4* outr = (float4*)(out + grow * EDIM);
        double lacc = 0.0;
#pragma unroll
        for (int i = 0; i < 16; ++i) {
            int k4 = q + i * 4;
            float4 zv = zp4[k4];
            float4 ev = ebr[k4];
            float4 o; float sd;
            sd = __fsub_rn(ev.x, zv.x); o.x = __fadd_rn(zv.x, sd); lacc += (double)__fmul_rn(sd, sd);
            sd = __fsub_rn(ev.y, zv.y); o.y = __fadd_rn(zv.y, sd); lacc += (double)__fmul_rn(sd, sd);
            sd = __fsub_rn(ev.z, zv.z); o.z = __fadd_rn(zv.z, sd); lacc += (double)__fmul_rn(sd, sd);
            sd = __fsub_rn(ev.w, zv.w); o.w = __fadd_rn(zv.w, sd); lacc += (double)__fmul_rn(sd, sd);
            outr[k4] = o;
        }
        if (q == 0) {
            out[OUT2 + grow] = (float)bn;
            atomicAdd(&count[bn], 1u);
        }
#pragma unroll
        for (int msk = 1; msk <= 32; msk <<= 1) lacc += __shfl_xor(lacc, msk);
        if (lane == 0) red4[w] = lacc;
        __syncthreads();
        if (tid == 0) atomicAdd(lossSum, red4[0] + red4[1] + red4[2] + red4[3]);
    }
}

__global__ void vq_finalize(const unsigned int* __restrict__ count,
                            const double* __restrict__ lossSum,
                            float* __restrict__ out)
{
    __shared__ double red[1024];
    int t = threadIdx.x;
    double em = (double)count[t] * (1.0 / 131072.0);
    red[t] = em * log(em + 1e-10);
    __syncthreads();
    for (int s = 512; s > 0; s >>= 1) {
        if (t < s) red[t] += red[t + s];
        __syncthreads();
    }
    if (t == 0) {
        out[OUT3] = (float)exp(-red[0]);
        double m = lossSum[0] * (1.0 / 33554432.0);
        out[OUT1] = (float)(1.25 * m);
    }
}

extern "C" void kernel_launch(void* const* d_in, const int* in_sizes, int n_in,
                              void* d_out, int out_size, void* d_ws, size_t ws_size,
                              hipStream_t stream) {
    const float* z   = (const float*)d_in[0];
    const float* emb = (const float*)d_in[1];
    float* out = (float*)d_out;

    unsigned short* embT = (unsigned short*)((char*)d_ws + WS_EMBT);
    float* esqg          = (float*)((char*)d_ws + WS_ESQ);
    unsigned int* count  = (unsigned int*)((char*)d_ws + WS_COUNT);
    double* lossSum      = (double*)((char*)d_ws + WS_LOSS);

    hipMemsetAsync((char*)d_ws + WS_COUNT, 0, 4104, stream);
    prep_emb<<<N_E, 64, 0, stream>>>(emb, embT, esqg);
    vq_main<<<B_ROWS / BMR, 256, 0, stream>>>(z, emb, embT, esqg, out, count, lossSum);
    vq_finalize<<<1, 1024, 0, stream>>>(count, lossSum, out);
}

// Round 10
// 341.894 us; speedup vs baseline: 42.6058x; 1.0116x over previous
//
#include <hip/hip_runtime.h>

typedef __attribute__((ext_vector_type(8))) __bf16 bf16x8;
typedef __attribute__((ext_vector_type(4))) float f32x4;
typedef __attribute__((ext_vector_type(8))) unsigned short u16x8;

#define B_ROWS 131072
#define EDIM   256
#define N_E    1024
#define BMR    64          // rows per block
#define CHUNKS 32          // 32 chunks x 32 codes (16 per nt-half)
#define CAP    16

#define OUT1 ((size_t)B_ROWS * EDIM)       // loss scalar
#define OUT2 (OUT1 + 1)                    // indices [B]
#define OUT3 (OUT2 + B_ROWS)               // perplexity scalar

// ws layout
#define WS_EMBT  0          // emb16T: [32 granules][1024 codes][8 bf16] = 524288 B
#define WS_ESQ   524288     // 1024 float
#define WS_COUNT 528384     // 1024 uint
#define WS_LOSS  532480     // 1 double

__device__ __forceinline__ unsigned short f2bf(float f) {   // RN to bf16
    unsigned u = __float_as_uint(f);
    return (unsigned short)((u + 0x7FFFu + ((u >> 16) & 1u)) >> 16);
}
__device__ __forceinline__ unsigned encf(float f) {          // order-preserving
    unsigned u = __float_as_uint(f);
    return u ^ (unsigned)(((int)u >> 31) | 0x80000000);
}
__device__ __forceinline__ float decf(unsigned x) {
    return (x & 0x80000000u) ? __uint_as_float(x ^ 0x80000000u)
                             : __uint_as_float(~x);
}
__device__ __forceinline__ float med3f(float a, float b, float c) {
#if __has_builtin(__builtin_amdgcn_fmed3f)
    return __builtin_amdgcn_fmed3f(a, b, c);
#else
    return fmaxf(fminf(a, b), fminf(fmaxf(a, b), c));
#endif
}

// numpy pairwise sum-of-squares over 128 elems (exact tree, no contraction)
__device__ inline float pw128_sq(const float* p) {
    float4 v0 = *(const float4*)p, v1 = *(const float4*)(p + 4);
    float r[8];
    r[0] = __fmul_rn(v0.x, v0.x); r[1] = __fmul_rn(v0.y, v0.y);
    r[2] = __fmul_rn(v0.z, v0.z); r[3] = __fmul_rn(v0.w, v0.w);
    r[4] = __fmul_rn(v1.x, v1.x); r[5] = __fmul_rn(v1.y, v1.y);
    r[6] = __fmul_rn(v1.z, v1.z); r[7] = __fmul_rn(v1.w, v1.w);
    for (int i = 8; i < 128; i += 8) {
        v0 = *(const float4*)(p + i); v1 = *(const float4*)(p + i + 4);
        r[0] = __fadd_rn(r[0], __fmul_rn(v0.x, v0.x));
        r[1] = __fadd_rn(r[1], __fmul_rn(v0.y, v0.y));
        r[2] = __fadd_rn(r[2], __fmul_rn(v0.z, v0.z));
        r[3] = __fadd_rn(r[3], __fmul_rn(v0.w, v0.w));
        r[4] = __fadd_rn(r[4], __fmul_rn(v1.x, v1.x));
        r[5] = __fadd_rn(r[5], __fmul_rn(v1.y, v1.y));
        r[6] = __fadd_rn(r[6], __fmul_rn(v1.z, v1.z));
        r[7] = __fadd_rn(r[7], __fmul_rn(v1.w, v1.w));
    }
    float s01 = __fadd_rn(r[0], r[1]), s23 = __fadd_rn(r[2], r[3]);
    float s45 = __fadd_rn(r[4], r[5]), s67 = __fadd_rn(r[6], r[7]);
    return __fadd_rn(__fadd_rn(s01, s23), __fadd_rn(s45, s67));
}

// exact fp32 distance, bit-identical to the verified rounds-1..9 chain
__device__ inline float exact_d(const float* zp, const float* ep, float zsq, float eq) {
    const float4* z4 = (const float4*)zp;
    const float4* e4 = (const float4*)ep;
    float acc = 0.f;
#pragma unroll 8
    for (int k = 0; k < 64; ++k) {
        float4 a = z4[k], b = e4[k];
        acc = __fmaf_rn(a.x, b.x, acc);
        acc = __fmaf_rn(a.y, b.y, acc);
        acc = __fmaf_rn(a.z, b.z, acc);
        acc = __fmaf_rn(a.w, b.w, acc);
    }
    return __fsub_rn(__fadd_rn(zsq, eq), 2.0f * acc);
}

// emb fp32 -> bf16, TRANSPOSED layout: embT[g][n] = 16B granule g of code n
__global__ void prep_emb(const float* __restrict__ emb,
                         unsigned short* __restrict__ embT,
                         float* __restrict__ esqg)
{
    int n = blockIdx.x, t = threadIdx.x;          // 1024 blocks x 64 threads
    const float4 v = ((const float4*)(emb + (size_t)n * EDIM))[t];
    ushort4 o = { f2bf(v.x), f2bf(v.y), f2bf(v.z), f2bf(v.w) };
    int g = t >> 1, j0 = (t & 1) * 4;
    *(ushort4*)(embT + ((size_t)g * N_E + n) * 8 + j0) = o;
    if (t < 2) {
        float h = pw128_sq(emb + (size_t)n * EDIM + 128 * t);
        float ho = __shfl_xor(h, 1);
        if (t == 0) esqg[n] = __fadd_rn(h, ho);
    }
}

__global__ __launch_bounds__(256, 3) void vq_main(
    const float* __restrict__ z, const float* __restrict__ emb,
    const unsigned short* __restrict__ embT, const float* __restrict__ esqg,
    float* __restrict__ out, unsigned int* __restrict__ count,
    double* __restrict__ lossSum)
{
    __shared__ float esq_s[N_E];                     // 4 KB
    __shared__ float zsq_s[BMR], S_s[BMR], thr_s[BMR];
    __shared__ unsigned long long wd64[2][BMR];      // 1 KB
    __shared__ unsigned cnt[BMR];
    __shared__ unsigned short list[BMR][CAP];        // 2 KB
    __shared__ int rowbest[BMR];
    __shared__ double red4[4];
    __shared__ unsigned long long fb4[4];

    const int tid  = threadIdx.x;
    const int blk  = blockIdx.x;
    const int lane = tid & 63;
    const int w    = tid >> 6;
    const int col  = lane & 15;
    const int quad = lane >> 4;
    const int nt   = w >> 1;       // code half within each 32-code chunk
    const int mh   = w & 1;        // row half (rows 32*mh..+32)

    const float* zb = z + (size_t)blk * BMR * EDIM;

    for (int i = tid; i < N_E; i += 256) esq_s[i] = esqg[i];
    if (tid < BMR) cnt[tid] = 0u;

    // ---- A fragments from global z (one-time) ----
    bf16x8 afr[2][8];
#pragma unroll
    for (int mti = 0; mti < 2; ++mti) {
        int row = 32 * mh + 16 * mti + col;
#pragma unroll
        for (int ks = 0; ks < 8; ++ks) {
            const float* p = zb + row * EDIM + ((ks * 4 + quad) << 3);
            float4 a0 = *(const float4*)p;
            float4 a1 = *(const float4*)(p + 4);
            u16x8 t = { f2bf(a0.x), f2bf(a0.y), f2bf(a0.z), f2bf(a0.w),
                        f2bf(a1.x), f2bf(a1.y), f2bf(a1.z), f2bf(a1.w) };
            afr[mti][ks] = *(bf16x8*)&t;
        }
    }

    // ---- exact zsq (np-pairwise) + S = sum|z| (bound only) ----
    if (tid < 128) {
        int row = tid >> 1, half = tid & 1;
        const float* p = zb + row * EDIM + half * 128;
        float h = pw128_sq(p);
        const float4* p4 = (const float4*)p;
        float4 sv = {0.f, 0.f, 0.f, 0.f};
#pragma unroll
        for (int jj = 0; jj < 32; ++jj) {
            float4 vv = p4[jj];
            sv.x += fabsf(vv.x); sv.y += fabsf(vv.y);
            sv.z += fabsf(vv.z); sv.w += fabsf(vv.w);
        }
        float sa = (sv.x + sv.y) + (sv.z + sv.w);
        float ho = __shfl_xor(h, 1);
        float so = __shfl_xor(sa, 1);
        if (half == 0) {
            zsq_s[row] = __fadd_rn(h, ho);
            S_s[row]   = (sa + so) * 1.001f;
        }
    }
    __syncthreads();

    // per-lane constant voffsets for the 8 B-granule loads (shorts)
    int koff[8];
#pragma unroll
    for (int ks = 0; ks < 8; ++ks)
        koff[ks] = (((ks * 4 + quad) << 10) + nt * 16 + col) * 8;

    // ================= barrier-free single-pass chunk loop =================
    // per slot: top-3 scores (bd1<=bd2<=bd3) + packed codes cp = c1 | (c2<<16)
    float bd1[2][4], bd2[2][4], bd3[2][4];
    int   cp_[2][4];
#pragma unroll
    for (int mti = 0; mti < 2; ++mti)
#pragma unroll
        for (int r = 0; r < 4; ++r) {
            bd1[mti][r] = INFINITY; bd2[mti][r] = INFINITY; bd3[mti][r] = INFINITY;
            cp_[mti][r] = 0;
        }

#pragma unroll 2
    for (int c = 0; c < CHUNKS; ++c) {
        const unsigned short* cb = embT + (c << 8);      // +c*32 codes (uniform)
        u16x8 bfr[8];
#pragma unroll
        for (int ks = 0; ks < 8; ++ks)
            bfr[ks] = *(const u16x8*)(cb + koff[ks]);
        f32x4 acc0 = {0.f, 0.f, 0.f, 0.f}, acc1 = {0.f, 0.f, 0.f, 0.f};
#pragma unroll
        for (int ks = 0; ks < 8; ++ks) {
            bf16x8 b = *(bf16x8*)&bfr[ks];
            acc0 = __builtin_amdgcn_mfma_f32_16x16x32_bf16(afr[0][ks], b, acc0, 0, 0, 0);
            acc1 = __builtin_amdgcn_mfma_f32_16x16x32_bf16(afr[1][ks], b, acc1, 0, 0, 0);
        }
        const int codeN = (c << 5) + nt * 16 + col;
        const float eqv = esq_s[codeN];
#pragma unroll
        for (int mti = 0; mti < 2; ++mti)
#pragma unroll
            for (int r = 0; r < 4; ++r) {
                float s = __fmaf_rn(-2.0f, (mti ? acc1[r] : acc0[r]), eqv);
                bool lt1 = s < bd1[mti][r];
                bool lt2 = s < bd2[mti][r];
                bd3[mti][r] = med3f(s, bd2[mti][r], bd3[mti][r]);
                bd2[mti][r] = med3f(s, bd1[mti][r], bd2[mti][r]);
                bd1[mti][r] = fminf(s, bd1[mti][r]);
                int cpo = cp_[mti][r];
                int low = cpo & 0xFFFF;
                cp_[mti][r] = lt1 ? (codeN | (low << 16))
                                  : (lt2 ? (low | (codeN << 16)) : cpo);
            }
    }

    // ---- cross-col reduce of bd1 (lex min on (score, code)) ----
#pragma unroll
    for (int mti = 0; mti < 2; ++mti)
#pragma unroll
        for (int r = 0; r < 4; ++r) {
            unsigned long long kk =
                ((unsigned long long)encf(bd1[mti][r]) << 32)
                | (unsigned)(cp_[mti][r] & 0xFFFF);
#pragma unroll
            for (int msk = 1; msk <= 8; msk <<= 1) {
                unsigned long long o = __shfl_xor(kk, msk);
                if (o < kk) kk = o;
            }
            if (col == 0) wd64[nt][32 * mh + 16 * mti + 4 * quad + r] = kk;
        }
    __syncthreads();
    if (tid < BMR) {
        unsigned long long a = wd64[0][tid], b = wd64[1][tid];
        unsigned long long mn = a < b ? a : b;
        thr_s[tid] = decf((unsigned)(mn >> 32)) + (S_s[tid] * (1.0f / 131072.0f) + 1e-4f);
    }
    __syncthreads();

    // ---- candidate push + overflow flag (top-3 soundness) ----
#pragma unroll
    for (int mti = 0; mti < 2; ++mti)
#pragma unroll
        for (int r = 0; r < 4; ++r) {
            int row = 32 * mh + 16 * mti + 4 * quad + r;
            float th = thr_s[row];
            if (__builtin_expect(bd1[mti][r] <= th, 0)) {
                unsigned i = atomicAdd(&cnt[row], 1u);
                if (i < CAP) list[row][i] = (unsigned short)(cp_[mti][r] & 0xFFFF);
            }
            if (__builtin_expect(bd2[mti][r] <= th, 0)) {
                unsigned i = atomicAdd(&cnt[row], 1u);
                if (i < CAP) list[row][i] = (unsigned short)((unsigned)cp_[mti][r] >> 16);
            }
            if (__builtin_expect(bd3[mti][r] <= th, 0))
                atomicAdd(&cnt[row], 1000u);     // may have dropped a candidate
        }
    __syncthreads();

    // ---- exact rescore of candidates (4 lanes / row, z from L2) ----
    {
        int row = tid >> 2, j = tid & 3;
        int cn = (int)cnt[row];
        unsigned long long bkey = ~0ull;
        float zq = zsq_s[row];
        const float* zrow = zb + row * EDIM;
        if (cn <= CAP) {
            for (int i = j; i < cn; i += 4) {
                int n = (int)list[row][i];
                float d = exact_d(zrow, emb + (size_t)n * EDIM, zq, esq_s[n]);
                unsigned long long k2 = ((unsigned long long)encf(d) << 32) | (unsigned)n;
                if (k2 < bkey) bkey = k2;
            }
        }
#pragma unroll
        for (int m = 1; m <= 2; m <<= 1) {
            unsigned long long o = __shfl_xor(bkey, m);
            if (o < bkey) bkey = o;
        }
        if (j == 0) rowbest[row] = (cn <= CAP) ? (int)(bkey & 0xFFFFFFFFu) : -1;
    }
    __syncthreads();

    // ---- overflow rows: full exact scan, block-cooperative (rare) ----
    for (int r = 0; r < BMR; ++r) {
        if (rowbest[r] != -1) continue;       // uniform branch
        const float* zr = zb + r * EDIM;
        float zqr = zsq_s[r];
        unsigned long long k = ~0ull;
        for (int ci = 0; ci < 4; ++ci) {
            int n = tid + ci * 256;
            float d = exact_d(zr, emb + (size_t)n * EDIM, zqr, esq_s[n]);
            unsigned long long k2 = ((unsigned long long)encf(d) << 32) | (unsigned)n;
            if (k2 < k) k = k2;
        }
#pragma unroll
        for (int msk = 1; msk <= 32; msk <<= 1) {
            unsigned long long o = __shfl_xor(k, msk);
            if (o < k) k = o;
        }
        if (lane == 0) fb4[w] = k;
        __syncthreads();
        if (tid == 0) {
            unsigned long long m0 = fb4[0] < fb4[1] ? fb4[0] : fb4[1];
            unsigned long long m1 = fb4[2] < fb4[3] ? fb4[2] : fb4[3];
            rowbest[r] = (int)((m0 < m1 ? m0 : m1) & 0xFFFFFFFFu);
        }
        __syncthreads();
    }

    // ---- epilogue: gather z_q, STE, loss partial, index, histogram ----
    {
        const int row = tid >> 2, q = tid & 3;
        const size_t grow = (size_t)blk * BMR + row;
        const int bn = rowbest[row];
        const float4* zp4 = (const float4*)(zb + row * EDIM);
        const float4* ebr = (const float4*)(emb + (size_t)bn * EDIM);
        float4* outr = (float4*)(out + grow * EDIM);
        double lacc = 0.0;
#pragma unroll
        for (int i = 0; i < 16; ++i) {
            int k4 = q + i * 4;
            float4 zv = zp4[k4];
            float4 ev = ebr[k4];
            float4 o; float sd;
            sd = __fsub_rn(ev.x, zv.x); o.x = __fadd_rn(zv.x, sd); lacc += (double)__fmul_rn(sd, sd);
            sd = __fsub_rn(ev.y, zv.y); o.y = __fadd_rn(zv.y, sd); lacc += (double)__fmul_rn(sd, sd);
            sd = __fsub_rn(ev.z, zv.z); o.z = __fadd_rn(zv.z, sd); lacc += (double)__fmul_rn(sd, sd);
            sd = __fsub_rn(ev.w, zv.w); o.w = __fadd_rn(zv.w, sd); lacc += (double)__fmul_rn(sd, sd);
            outr[k4] = o;
        }
        if (q == 0) {
            out[OUT2 + grow] = (float)bn;
            atomicAdd(&count[bn], 1u);
        }
#pragma unroll
        for (int msk = 1; msk <= 32; msk <<= 1) lacc += __shfl_xor(lacc, msk);
        if (lane == 0) red4[w] = lacc;
        __syncthreads();
        if (tid == 0) atomicAdd(lossSum, red4[0] + red4[1] + red4[2] + red4[3]);
    }
}

__global__ void vq_finalize(const unsigned int* __restrict__ count,
                            const double* __restrict__ lossSum,
                            float* __restrict__ out)
{
    __shared__ double red[1024];
    int t = threadIdx.x;
    double em = (double)count[t] * (1.0 / 131072.0);
    red[t] = em * log(em + 1e-10);
    __syncthreads();
    for (int s = 512; s > 0; s >>= 1) {
        if (t < s) red[t] += red[t + s];
        __syncthreads();
    }
    if (t == 0) {
        out[OUT3] = (float)exp(-red[0]);
        double m = lossSum[0] * (1.0 / 33554432.0);
        out[OUT1] = (float)(1.25 * m);
    }
}

extern "C" void kernel_launch(void* const* d_in, const int* in_sizes, int n_in,
                              void* d_out, int out_size, void* d_ws, size_t ws_size,
                              hipStream_t stream) {
    const float* z   = (const float*)d_in[0];
    const float* emb = (const float*)d_in[1];
    float* out = (float*)d_out;

    unsigned short* embT = (unsigned short*)((char*)d_ws + WS_EMBT);
    float* esqg          = (float*)((char*)d_ws + WS_ESQ);
    unsigned int* count  = (unsigned int*)((char*)d_ws + WS_COUNT);
    double* lossSum      = (double*)((char*)d_ws + WS_LOSS);

    hipMemsetAsync((char*)d_ws + WS_COUNT, 0, 4104, stream);
    prep_emb<<<N_E, 64, 0, stream>>>(emb, embT, esqg);
    vq_main<<<B_ROWS / BMR, 256, 0, stream>>>(z, emb, embT, esqg, out, count, lossSum);
    vq_finalize<<<1, 1024, 0, stream>>>(count, lossSum, out);
}